// Round 7
// baseline (1965.846 us; speedup 1.0000x reference)
//
#include <hip/hip_runtime.h>
#include <hip/hip_bf16.h>
#include <cstdint>
#include <cstddef>

// DeepGPCM / DKVMN recurrence.
//  - erase/add are pure functions of (q,r): precomputed table EAD[(q-1)*4+r][d] = {erase,add}.
//  - attention softmax pure function of q: precomputed CW[q][50].
//  - per-question tables SQ (Ws_q*qe+bs), BQ (tanh betas), DQ (Wdisc_q*qe).
//  - main kernel: 512 threads / block (8 waves), 1 block / batch element.
//    Mv column d split across TWO threads (half0: pairs 0-12, half1: pairs 13-24) ->
//    phase-1 issue cost per wave halves, and waves are balanced:
//      wave0: finale + cw staging (no phase1)
//      wave1: 16 dact lanes + sq staging
//      waves2-3: phase1 only
//      waves4-7: phase1 + phase2
//    read_d partials stored as f16 in two LDS arrays, combined in phase2 via v_pk_add_f16.
//    Single lds-only barrier per step (all buffers cross-step double/triple-buffered).
//  - __launch_bounds__(512,8): VGPR<=64 -> 32 waves/CU (grid 1024 = 4 blocks/CU).

namespace {
constexpr int kB   = 1024;
constexpr int kS   = 500;
constexpr int kQ   = 2000;
constexpr int kKD  = 50;
constexpr int kMem = 50;
constexpr int kD   = 200;
constexpr int kFC  = 50;
constexpr int kWP  = 216;  // f16 pitch for s_wsh rows

// ws layout in floats
constexpr size_t OFF_EAD  = 0;                              // 2000*4*200*2 = 3,200,000
constexpr size_t OFF_CW   = OFF_EAD + (size_t)kQ * 4 * kD * 2;
constexpr size_t OFF_SQ   = OFF_CW + 100064;                // CW: 2001*50
constexpr size_t OFF_BQ   = OFF_SQ + 100064;                // SQ: 2001*50
constexpr size_t OFF_DQ   = OFF_BQ + 8032;                  // BQ: 2001*4
constexpr size_t OFF_CE   = OFF_DQ + 2016;                  // DQ: 2001
constexpr size_t OFF_CA   = OFF_CE + 224;
constexpr size_t OFF_WET  = OFF_CA + 224;
constexpr size_t OFF_WAT  = OFF_WET + 40000;
}  // namespace

typedef float f32x2 __attribute__((ext_vector_type(2)));
typedef _Float16 h2_t __attribute__((ext_vector_type(2)));

__device__ __forceinline__ f32x2 pk_fma(f32x2 a, f32x2 b, f32x2 c) {
  f32x2 d;
  asm("v_pk_fma_f32 %0, %1, %2, %3" : "=v"(d) : "v"(a), "v"(b), "v"(c));
  return d;
}

__device__ __forceinline__ void lds_barrier() {
  asm volatile("s_waitcnt lgkmcnt(0)" ::: "memory");
  __builtin_amdgcn_s_barrier();
  asm volatile("" ::: "memory");
}

__device__ __forceinline__ float fast_tanh(float x) {
  const float ax = fabsf(x);
  const float t = __expf(-2.f * ax);
  const float r = (1.f - t) / (1.f + t);
  return copysignf(r, x);
}
__device__ __forceinline__ float fast_softplus(float x) {
  return fmaxf(x, 0.f) + log1pf(__expf(-fabsf(x)));
}

// ---------------- prep 1: transposes + bias folds ----------------
__global__ void prep1_misc(const float* __restrict__ We, const float* __restrict__ Wa,
                           const float* __restrict__ bv, const float* __restrict__ be,
                           const float* __restrict__ ba, float* __restrict__ ws) {
  float* WeT = ws + OFF_WET;
  float* WaT = ws + OFF_WAT;
  float* ce  = ws + OFF_CE;
  float* ca  = ws + OFF_CA;
  const int gt = blockIdx.x * 256 + threadIdx.x;
  const int stride = gridDim.x * 256;
  for (int e = gt; e < kD * kD; e += stride) {
    const int i = e / kD;
    const int dd = e - i * kD;
    WeT[e] = We[dd * kD + i];
    WaT[e] = Wa[dd * kD + i];
  }
  for (int dd = gt; dd < kD; dd += stride) {
    float acc_e = be[dd], acc_a = ba[dd];
    for (int i = 0; i < kD; ++i) {
      acc_e = fmaf(We[dd * kD + i], bv[i], acc_e);
      acc_a = fmaf(Wa[dd * kD + i], bv[i], acc_a);
    }
    ce[dd] = acc_e;
    ca[dd] = acc_a;
  }
}

// ---------------- prep 2: EAD table = {sigmoid(We@ve+be), tanh(Wa@ve+ba)} per (q,r,d) ----
__global__ void prep2_ead(const float* __restrict__ Wv, float* __restrict__ ws) {
  __shared__ float s_wv[4][kD];
  const int tid = threadIdx.x;
  const int qm1 = blockIdx.x;  // question-1 in [0,2000)
  for (int e = tid; e < 4 * kD; e += 256) {
    const int k = e / kD;
    const int i = e - k * kD;
    s_wv[k][i] = Wv[(size_t)i * (4 * kQ) + (size_t)k * kQ + qm1];
  }
  __syncthreads();
  const int d = tid;
  if (d < kD) {
    const float* WeT = ws + OFF_WET;
    const float* WaT = ws + OFF_WAT;
    float e0 = 0.f, e1 = 0.f, e2 = 0.f, e3 = 0.f;
    float a0 = 0.f, a1 = 0.f, a2 = 0.f, a3 = 0.f;
    for (int i = 0; i < kD; ++i) {
      const float we = WeT[i * kD + d];
      const float wa = WaT[i * kD + d];
      e0 = fmaf(we, s_wv[0][i], e0);
      e1 = fmaf(we, s_wv[1][i], e1);
      e2 = fmaf(we, s_wv[2][i], e2);
      e3 = fmaf(we, s_wv[3][i], e3);
      a0 = fmaf(wa, s_wv[0][i], a0);
      a1 = fmaf(wa, s_wv[1][i], a1);
      a2 = fmaf(wa, s_wv[2][i], a2);
      a3 = fmaf(wa, s_wv[3][i], a3);
    }
    const float ced = ws[OFF_CE + d];
    const float cad = ws[OFF_CA + d];
    const float W[4][4] = {{1.f, 2.f / 3.f, 1.f / 3.f, 0.f},
                           {2.f / 3.f, 1.f, 2.f / 3.f, 1.f / 3.f},
                           {1.f / 3.f, 2.f / 3.f, 1.f, 2.f / 3.f},
                           {0.f, 1.f / 3.f, 2.f / 3.f, 1.f}};
#pragma unroll
    for (int r = 0; r < 4; ++r) {
      const float ep = ced + W[r][0] * e0 + W[r][1] * e1 + W[r][2] * e2 + W[r][3] * e3;
      const float ap = cad + W[r][0] * a0 + W[r][1] * a1 + W[r][2] * a2 + W[r][3] * a3;
      float2 v;
      v.x = 1.f / (1.f + expf(-ep));  // erase
      v.y = tanhf(ap);                // add
      *reinterpret_cast<float2*>(ws + OFF_EAD + ((size_t)(qm1 * 4 + r) * kD + d) * 2) = v;
    }
  }
}

// ---------------- prep 3: per-question tables CW/SQ/BQ/DQ ----------------
__global__ void prep3_qtables(const float* __restrict__ q_embed_w, const float* __restrict__ Mk,
                              const float* __restrict__ Ws, const float* __restrict__ bs,
                              const float* __restrict__ Wbeta, const float* __restrict__ bbeta,
                              const float* __restrict__ Wdisc, float* __restrict__ ws) {
  __shared__ float s_qe[kKD];
  const int tid = threadIdx.x;
  const int q = blockIdx.x;  // 0..2000
  if (tid < kKD) s_qe[tid] = q_embed_w[q * kKD + tid];
  __syncthreads();
  {
    float s = -1e30f;
    if (tid < kMem) {
      s = 0.f;
      for (int j = 0; j < kKD; ++j) s = fmaf(s_qe[j], Mk[tid * kKD + j], s);
    }
    float mx = s;
#pragma unroll
    for (int o = 1; o < 64; o <<= 1) mx = fmaxf(mx, __shfl_xor(mx, o));
    const float ev = (tid < kMem) ? expf(s - mx) : 0.f;
    float sm = ev;
#pragma unroll
    for (int o = 1; o < 64; o <<= 1) sm += __shfl_xor(sm, o);
    if (tid < kMem) ws[OFF_CW + (size_t)q * kMem + tid] = ev / sm;
  }
  if (tid < kFC) {
    float s = bs[tid];
    for (int j = 0; j < kKD; ++j) s = fmaf(s_qe[j], Ws[tid * 250 + kD + j], s);
    ws[OFF_SQ + (size_t)q * kFC + tid] = s;
  }
  if (tid < 4) {
    float v = 0.f;
    if (tid < 3) {
      float s = bbeta[tid];
      for (int j = 0; j < kKD; ++j) s = fmaf(s_qe[j], Wbeta[tid * kKD + j], s);
      v = tanhf(s);
    }
    ws[OFF_BQ + (size_t)q * 4 + tid] = v;
  }
  if (tid == 0) {
    float s = 0.f;
    for (int j = 0; j < kKD; ++j) s = fmaf(s_qe[j], Wdisc[kFC + j], s);
    ws[OFF_DQ + q] = s;
  }
}

// ---------------- main recurrent kernel ----------------
__device__ __forceinline__ void do_finale(int l, float wth_f, float wds_f, float bth0,
                                          float bdisc0, const float (*s_part)[64],
                                          const float* s_sq_row, const float* s_bqdq_row,
                                          float* out_ptr) {
  float summ = 0.f;
  if (l < kFC) {
    const float sp = s_part[0][l] + s_part[1][l] + s_part[2][l] + s_part[3][l] +
                     s_part[4][l] + s_sq_row[l];
    summ = fast_tanh(sp);
  }
  float p1 = wth_f * summ;
  float p2 = wds_f * summ;
#pragma unroll
  for (int o = 1; o < 64; o <<= 1) {
    p1 += __shfl_xor(p1, o);
    p2 += __shfl_xor(p2, o);
  }
  if (l == 0) {
    const float theta = 3.f * (p1 + bth0);
    const float alpha = fast_softplus(p2 + s_bqdq_row[3] + bdisc0);
    const float c1 = alpha * (theta - s_bqdq_row[0]);
    const float c2 = c1 + alpha * (theta - s_bqdq_row[1]);
    const float c3 = c2 + alpha * (theta - s_bqdq_row[2]);
    const float mx = fmaxf(fmaxf(0.f, c1), fmaxf(c2, c3));
    const float x0 = __expf(0.f - mx);
    const float x1 = __expf(c1 - mx);
    const float x2 = __expf(c2 - mx);
    const float x3 = __expf(c3 - mx);
    const float inv = 1.f / (x0 + x1 + x2 + x3);
    float4 pr;
    pr.x = x0 * inv;
    pr.y = x1 * inv;
    pr.z = x2 * inv;
    pr.w = x3 * inv;
    *reinterpret_cast<float4*>(out_ptr) = pr;
  }
}

__launch_bounds__(512, 8)
__global__ void dkvmn_main(const int* __restrict__ q_data, const int* __restrict__ r_data,
                           const float* __restrict__ Mv0, const float* __restrict__ Ws,
                           const float* __restrict__ Wth, const float* __restrict__ bth,
                           const float* __restrict__ Wdisc, const float* __restrict__ bdisc,
                           const float* __restrict__ ws, float* __restrict__ out) {
  const int tid = threadIdx.x;
  const int b = blockIdx.x;
  const int lane = tid & 63;
  const int wid = tid >> 6;
  const float* EAD = ws + OFF_EAD;
  const float* CW = ws + OFF_CW;
  const float* SQ = ws + OFF_SQ;
  const float* BQ = ws + OFF_BQ;
  const float* DQ = ws + OFF_DQ;

  __shared__ __align__(16) _Float16 s_wsh[kFC * kWP];   // f16 Ws(:,0:200) [f][d], pitch 216
  __shared__ __align__(16) _Float16 s_readh[2][2][208]; // [buf][half][d] f16 partial reads
  __shared__ __align__(16) float s_cw[2][64];
  __shared__ float s_part[2][5][64];
  __shared__ float s_sq[3][52];
  __shared__ float s_bqdq[3][4];
  __shared__ int s_q[kS];
  __shared__ int s_qr[kS];

  for (int e = tid; e < kFC * kD; e += 512) {
    const int f = e / kD;
    const int dd = e - f * kD;
    s_wsh[f * kWP + dd] = (_Float16)Ws[f * 250 + dd];
  }
  {
    const int* qrow = q_data + (size_t)b * kS;
    const int* rrow = r_data + (size_t)b * kS;
    for (int e = tid; e < kS; e += 512) {
      const int qv = qrow[e];
      s_q[e] = qv;
      s_qr[e] = (qv - 1) * 4 + rrow[e];
    }
  }
  // ---- role mapping ----
  // dact: tid in [112,512): u = tid-112; half1 = u>=200; d = u - (half1?200:0)
  //   half0 owns pairs 0..12 (mem slots 0..25); half1 owns pairs 13..24 (slots 26..49)
  // phase2: tid in [262,512): idx = tid-262 -> (pc, pf)
  // finale + cw staging: wave0.  sq staging: wave1 lanes<54.
  const bool dact = (tid >= 112);
  const int u = tid - 112;
  const bool half1 = (u >= 200);
  const int d = half1 ? (u - 200) : u;
  const int p0 = half1 ? 13 : 0;

  const bool pact = (tid >= 262);
  const int pidx = tid - 262;
  const int pc = pidx / 50;
  const int pf = pidx - pc * 50;

  f32x2 mv[13];
#pragma unroll
  for (int j = 0; j < 13; ++j) mv[j] = f32x2{0.f, 0.f};
  if (dact) {
#pragma unroll
    for (int j = 0; j < 12; ++j) {
      const int m2 = 2 * (p0 + j);
      mv[j][0] = Mv0[m2 * kD + d];
      mv[j][1] = Mv0[(m2 + 1) * kD + d];
    }
    if (!half1) {
      mv[12][0] = Mv0[24 * kD + d];
      mv[12][1] = Mv0[25 * kD + d];
    }
  }
  float wth_f = 0.f, wds_f = 0.f;
  if (wid == 0 && lane < kFC) {
    wth_f = Wth[lane];
    wds_f = Wdisc[lane];
  }
  const float bth0 = bth[0];
  const float bdisc0 = bdisc[0];
  float* out_b = out + (size_t)b * kS * 4;
  __syncthreads();  // init fills visible

  // prologue: stage step-0 consumables + register prefetch
  const int q0 = s_q[0];
  const int q1 = s_q[1];
  float2 ea_cur = make_float2(0.f, 0.f);
  if (dact) ea_cur = *(reinterpret_cast<const float2*>(EAD) + (s_qr[0] * kD + d));
  float cw_cur = 0.f;
  if (wid == 0 && lane < kMem) {
    s_cw[0][lane] = CW[q0 * kMem + lane];
    cw_cur = CW[q1 * kMem + lane];
  }
  float v2_cur = 0.f;
  if (wid == 1) {
    if (lane < kFC) v2_cur = SQ[q0 * kFC + lane];
    else if (lane < 53) v2_cur = BQ[q0 * 4 + (lane - 50)];
    else if (lane == 53) v2_cur = DQ[q0];
  }
  __syncthreads();  // s_cw[0] visible

  int i3 = 0;  // t % 3
  for (int t = 0; t < kS; ++t) {
    const int pb = t & 1;
    const int ip1 = (i3 + 1 < 3) ? i3 + 1 : 0;  // (t+1)%3 == (t-2)%3
    const int tn1 = (t + 1 < kS) ? t + 1 : kS - 1;
    const int tn2 = (t + 2 < kS) ? t + 2 : kS - 1;
    // ---- prefetch + staging ----
    f32x2 en2 = {0.f, 0.f}, ad2 = {0.f, 0.f};
    float2 ea_nxt = ea_cur;
    if (dact) {
      ea_nxt = *(reinterpret_cast<const float2*>(EAD) + (s_qr[tn1] * kD + d));
      en2[0] = -ea_cur.x;
      en2[1] = -ea_cur.x;
      ad2[0] = ea_cur.y;
      ad2[1] = ea_cur.y;
    }
    if (wid == 0 && lane < kMem) {  // cw for step t+1; prefetch t+2
      s_cw[pb ^ 1][lane] = cw_cur;
      cw_cur = CW[s_q[tn2] * kMem + lane];
    }
    if (wid == 1) {  // head inputs for step t (finale consumes at t+2); prefetch t+1
      const int qn = s_q[tn1];
      if (lane < kFC) {
        s_sq[i3][lane] = v2_cur;
        v2_cur = SQ[qn * kFC + lane];
      } else if (lane < 53) {
        s_bqdq[i3][lane - 50] = v2_cur;
        v2_cur = BQ[qn * 4 + (lane - 50)];
      } else if (lane == 53) {
        s_bqdq[i3][3] = v2_cur;
        v2_cur = DQ[qn];
      }
    }
    // ---- phase 1: Mv update + partial read (consumes s_cw[pb]) ----
    if (dact) {
      f32x2 r2a = {0.f, 0.f}, r2b = {0.f, 0.f};
      const f32x2* cw2 = reinterpret_cast<const f32x2*>(s_cw[pb]) + p0;
#pragma unroll
      for (int j = 0; j < 12; ++j) {
        const f32x2 c2 = cw2[j];
        if (j & 1) {
          r2b = pk_fma(c2, mv[j], r2b);
        } else {
          r2a = pk_fma(c2, mv[j], r2a);
        }
        mv[j] = pk_fma(c2, pk_fma(mv[j], en2, ad2), mv[j]);
      }
      if (!half1) {
        const f32x2 c2 = cw2[12];
        r2a = pk_fma(c2, mv[12], r2a);
        mv[12] = pk_fma(c2, pk_fma(mv[12], en2, ad2), mv[12]);
      }
      s_readh[pb][half1][d] = (_Float16)((r2a[0] + r2b[0]) + (r2a[1] + r2b[1]));
    }
    // ---- finale for step t-2 (wave0) ----
    if (wid == 0 && t >= 2) {
      do_finale(lane, wth_f, wds_f, bth0, bdisc0, s_part[pb ^ 1], s_sq[ip1], s_bqdq[ip1],
                out_b + (size_t)(t - 2) * 4);
    }
    // ---- phase 2: summary partials from read[t-1] ----
    if (pact) {
      const float4* wp = reinterpret_cast<const float4*>(s_wsh + pf * kWP + pc * 40);
      const float4* rpA = reinterpret_cast<const float4*>(&s_readh[pb ^ 1][0][pc * 40]);
      const float4* rpB = reinterpret_cast<const float4*>(&s_readh[pb ^ 1][1][pc * 40]);
      float acc0 = 0.f, acc1 = 0.f;
#pragma unroll
      for (int g = 0; g < 5; ++g) {
        const float4 wv = wp[g];
        const float4 va = rpA[g];
        const float4 vb = rpB[g];
        const h2_t r0 = __builtin_bit_cast(h2_t, va.x) + __builtin_bit_cast(h2_t, vb.x);
        const h2_t r1 = __builtin_bit_cast(h2_t, va.y) + __builtin_bit_cast(h2_t, vb.y);
        const h2_t r2 = __builtin_bit_cast(h2_t, va.z) + __builtin_bit_cast(h2_t, vb.z);
        const h2_t r3 = __builtin_bit_cast(h2_t, va.w) + __builtin_bit_cast(h2_t, vb.w);
        acc0 = __builtin_amdgcn_fdot2(__builtin_bit_cast(h2_t, wv.x), r0, acc0, false);
        acc1 = __builtin_amdgcn_fdot2(__builtin_bit_cast(h2_t, wv.y), r1, acc1, false);
        acc0 = __builtin_amdgcn_fdot2(__builtin_bit_cast(h2_t, wv.z), r2, acc0, false);
        acc1 = __builtin_amdgcn_fdot2(__builtin_bit_cast(h2_t, wv.w), r3, acc1, false);
      }
      s_part[pb][pc][pf] = acc0 + acc1;
    }
    lds_barrier();  // single per-step barrier
    ea_cur = ea_nxt;
    i3 = ip1;
  }
  // ---- epilogue: drain 2-deep pipeline (steps kS-2, kS-1) ----
  {
    constexpr int pbE = kS & 1;        // 0 for kS=500
    constexpr int i3a = (kS - 2) % 3;
    constexpr int i3b = (kS - 1) % 3;
    if (pact) {  // partials from read[kS-1] (in s_readh[(kS-1)&1])
      const float4* wp = reinterpret_cast<const float4*>(s_wsh + pf * kWP + pc * 40);
      const float4* rpA = reinterpret_cast<const float4*>(&s_readh[(kS - 1) & 1][0][pc * 40]);
      const float4* rpB = reinterpret_cast<const float4*>(&s_readh[(kS - 1) & 1][1][pc * 40]);
      float acc0 = 0.f, acc1 = 0.f;
#pragma unroll
      for (int g = 0; g < 5; ++g) {
        const float4 wv = wp[g];
        const float4 va = rpA[g];
        const float4 vb = rpB[g];
        const h2_t r0 = __builtin_bit_cast(h2_t, va.x) + __builtin_bit_cast(h2_t, vb.x);
        const h2_t r1 = __builtin_bit_cast(h2_t, va.y) + __builtin_bit_cast(h2_t, vb.y);
        const h2_t r2 = __builtin_bit_cast(h2_t, va.z) + __builtin_bit_cast(h2_t, vb.z);
        const h2_t r3 = __builtin_bit_cast(h2_t, va.w) + __builtin_bit_cast(h2_t, vb.w);
        acc0 = __builtin_amdgcn_fdot2(__builtin_bit_cast(h2_t, wv.x), r0, acc0, false);
        acc1 = __builtin_amdgcn_fdot2(__builtin_bit_cast(h2_t, wv.y), r1, acc1, false);
        acc0 = __builtin_amdgcn_fdot2(__builtin_bit_cast(h2_t, wv.z), r2, acc0, false);
        acc1 = __builtin_amdgcn_fdot2(__builtin_bit_cast(h2_t, wv.w), r3, acc1, false);
      }
      s_part[pbE][pc][pf] = acc0 + acc1;
    }
    if (wid == 0) {  // finale for step kS-2 (partials written at t=kS-1)
      do_finale(lane, wth_f, wds_f, bth0, bdisc0, s_part[pbE ^ 1], s_sq[i3a], s_bqdq[i3a],
                out_b + (size_t)(kS - 2) * 4);
    }
    lds_barrier();
    if (wid == 0) {  // finale for step kS-1
      do_finale(lane, wth_f, wds_f, bth0, bdisc0, s_part[pbE], s_sq[i3b], s_bqdq[i3b],
                out_b + (size_t)(kS - 1) * 4);
    }
  }
}

extern "C" void kernel_launch(void* const* d_in, const int* in_sizes, int n_in,
                              void* d_out, int out_size, void* d_ws, size_t ws_size,
                              hipStream_t stream) {
  (void)in_sizes; (void)n_in; (void)out_size; (void)ws_size;
  const int* q_data = (const int*)d_in[0];
  const int* r_data = (const int*)d_in[1];
  const float* q_embed_w = (const float*)d_in[2];
  const float* Mk = (const float*)d_in[3];
  const float* Mv0 = (const float*)d_in[4];
  const float* Wv = (const float*)d_in[5];
  const float* bv = (const float*)d_in[6];
  const float* We = (const float*)d_in[7];
  const float* be = (const float*)d_in[8];
  const float* Wa = (const float*)d_in[9];
  const float* ba = (const float*)d_in[10];
  const float* Ws = (const float*)d_in[11];
  const float* bs = (const float*)d_in[12];
  const float* Wth = (const float*)d_in[13];
  const float* bth = (const float*)d_in[14];
  const float* Wbeta = (const float*)d_in[15];
  const float* bbeta = (const float*)d_in[16];
  const float* Wdisc = (const float*)d_in[17];
  const float* bdisc = (const float*)d_in[18];
  float* out = (float*)d_out;
  float* ws = (float*)d_ws;

  hipLaunchKernelGGL(prep1_misc, dim3(64), dim3(256), 0, stream, We, Wa, bv, be, ba, ws);
  hipLaunchKernelGGL(prep2_ead, dim3(kQ), dim3(256), 0, stream, Wv, ws);
  hipLaunchKernelGGL(prep3_qtables, dim3(kQ + 1), dim3(64), 0, stream, q_embed_w, Mk, Ws, bs,
                     Wbeta, bbeta, Wdisc, ws);
  hipLaunchKernelGGL(dkvmn_main, dim3(kB), dim3(512), 0, stream, q_data, r_data, Mv0, Ws, Wth,
                     bth, Wdisc, bdisc, ws, out);
}

// Round 8
// 1476.088 us; speedup vs baseline: 1.3318x; 1.3318x over previous
//
#include <hip/hip_runtime.h>
#include <hip/hip_bf16.h>
#include <cstdint>
#include <cstddef>

// DeepGPCM / DKVMN recurrence.
//  - erase/add are pure functions of (q,r): precomputed table EAD[(q-1)*4+r][d] = {erase,add}.
//  - attention softmax pure function of q: precomputed CW[q][50].
//  - per-question tables SQ (Ws_q*qe+bs), BQ (tanh betas), DQ (Wdisc_q*qe).
//  - main kernel: 512 threads / block (8 waves), 1 block / batch element.
//    Mv column d split across TWO threads (half0: pairs 0-12, half1: pairs 13-24).
//    Single lds-only barrier per step; all LDS buffers cross-step double/triple-buffered.
//  - __launch_bounds__(512, 4): second arg is BLOCKS/CU (CUDA semantics in this toolchain).
//    R7's (512,8) made the compiler target 64 waves/CU -> 32-VGPR cap -> 2.2 GB of scratch
//    spill traffic per dispatch. (512,4) = 32 waves/CU, 64-VGPR cap, fits the ~50-reg
//    working set without spilling.

namespace {
constexpr int kB   = 1024;
constexpr int kS   = 500;
constexpr int kQ   = 2000;
constexpr int kKD  = 50;
constexpr int kMem = 50;
constexpr int kD   = 200;
constexpr int kFC  = 50;
constexpr int kWP  = 216;  // f16 pitch for s_wsh rows

// ws layout in floats
constexpr size_t OFF_EAD  = 0;                              // 2000*4*200*2 = 3,200,000
constexpr size_t OFF_CW   = OFF_EAD + (size_t)kQ * 4 * kD * 2;
constexpr size_t OFF_SQ   = OFF_CW + 100064;                // CW: 2001*50
constexpr size_t OFF_BQ   = OFF_SQ + 100064;                // SQ: 2001*50
constexpr size_t OFF_DQ   = OFF_BQ + 8032;                  // BQ: 2001*4
constexpr size_t OFF_CE   = OFF_DQ + 2016;                  // DQ: 2001
constexpr size_t OFF_CA   = OFF_CE + 224;
constexpr size_t OFF_WET  = OFF_CA + 224;
constexpr size_t OFF_WAT  = OFF_WET + 40000;
}  // namespace

typedef float f32x2 __attribute__((ext_vector_type(2)));
typedef _Float16 h2_t __attribute__((ext_vector_type(2)));

__device__ __forceinline__ f32x2 pk_fma(f32x2 a, f32x2 b, f32x2 c) {
  f32x2 d;
  asm("v_pk_fma_f32 %0, %1, %2, %3" : "=v"(d) : "v"(a), "v"(b), "v"(c));
  return d;
}

__device__ __forceinline__ void lds_barrier() {
  asm volatile("s_waitcnt lgkmcnt(0)" ::: "memory");
  __builtin_amdgcn_s_barrier();
  asm volatile("" ::: "memory");
}

__device__ __forceinline__ float fast_tanh(float x) {
  const float ax = fabsf(x);
  const float t = __expf(-2.f * ax);
  const float r = (1.f - t) / (1.f + t);
  return copysignf(r, x);
}
__device__ __forceinline__ float fast_softplus(float x) {
  return fmaxf(x, 0.f) + log1pf(__expf(-fabsf(x)));
}

// ---------------- prep 1: transposes + bias folds ----------------
__global__ void prep1_misc(const float* __restrict__ We, const float* __restrict__ Wa,
                           const float* __restrict__ bv, const float* __restrict__ be,
                           const float* __restrict__ ba, float* __restrict__ ws) {
  float* WeT = ws + OFF_WET;
  float* WaT = ws + OFF_WAT;
  float* ce  = ws + OFF_CE;
  float* ca  = ws + OFF_CA;
  const int gt = blockIdx.x * 256 + threadIdx.x;
  const int stride = gridDim.x * 256;
  for (int e = gt; e < kD * kD; e += stride) {
    const int i = e / kD;
    const int dd = e - i * kD;
    WeT[e] = We[dd * kD + i];
    WaT[e] = Wa[dd * kD + i];
  }
  for (int dd = gt; dd < kD; dd += stride) {
    float acc_e = be[dd], acc_a = ba[dd];
    for (int i = 0; i < kD; ++i) {
      acc_e = fmaf(We[dd * kD + i], bv[i], acc_e);
      acc_a = fmaf(Wa[dd * kD + i], bv[i], acc_a);
    }
    ce[dd] = acc_e;
    ca[dd] = acc_a;
  }
}

// ---------------- prep 2: EAD table = {sigmoid(We@ve+be), tanh(Wa@ve+ba)} per (q,r,d) ----
__global__ void prep2_ead(const float* __restrict__ Wv, float* __restrict__ ws) {
  __shared__ float s_wv[4][kD];
  const int tid = threadIdx.x;
  const int qm1 = blockIdx.x;  // question-1 in [0,2000)
  for (int e = tid; e < 4 * kD; e += 256) {
    const int k = e / kD;
    const int i = e - k * kD;
    s_wv[k][i] = Wv[(size_t)i * (4 * kQ) + (size_t)k * kQ + qm1];
  }
  __syncthreads();
  const int d = tid;
  if (d < kD) {
    const float* WeT = ws + OFF_WET;
    const float* WaT = ws + OFF_WAT;
    float e0 = 0.f, e1 = 0.f, e2 = 0.f, e3 = 0.f;
    float a0 = 0.f, a1 = 0.f, a2 = 0.f, a3 = 0.f;
    for (int i = 0; i < kD; ++i) {
      const float we = WeT[i * kD + d];
      const float wa = WaT[i * kD + d];
      e0 = fmaf(we, s_wv[0][i], e0);
      e1 = fmaf(we, s_wv[1][i], e1);
      e2 = fmaf(we, s_wv[2][i], e2);
      e3 = fmaf(we, s_wv[3][i], e3);
      a0 = fmaf(wa, s_wv[0][i], a0);
      a1 = fmaf(wa, s_wv[1][i], a1);
      a2 = fmaf(wa, s_wv[2][i], a2);
      a3 = fmaf(wa, s_wv[3][i], a3);
    }
    const float ced = ws[OFF_CE + d];
    const float cad = ws[OFF_CA + d];
    const float W[4][4] = {{1.f, 2.f / 3.f, 1.f / 3.f, 0.f},
                           {2.f / 3.f, 1.f, 2.f / 3.f, 1.f / 3.f},
                           {1.f / 3.f, 2.f / 3.f, 1.f, 2.f / 3.f},
                           {0.f, 1.f / 3.f, 2.f / 3.f, 1.f}};
#pragma unroll
    for (int r = 0; r < 4; ++r) {
      const float ep = ced + W[r][0] * e0 + W[r][1] * e1 + W[r][2] * e2 + W[r][3] * e3;
      const float ap = cad + W[r][0] * a0 + W[r][1] * a1 + W[r][2] * a2 + W[r][3] * a3;
      float2 v;
      v.x = 1.f / (1.f + expf(-ep));  // erase
      v.y = tanhf(ap);                // add
      *reinterpret_cast<float2*>(ws + OFF_EAD + ((size_t)(qm1 * 4 + r) * kD + d) * 2) = v;
    }
  }
}

// ---------------- prep 3: per-question tables CW/SQ/BQ/DQ ----------------
__global__ void prep3_qtables(const float* __restrict__ q_embed_w, const float* __restrict__ Mk,
                              const float* __restrict__ Ws, const float* __restrict__ bs,
                              const float* __restrict__ Wbeta, const float* __restrict__ bbeta,
                              const float* __restrict__ Wdisc, float* __restrict__ ws) {
  __shared__ float s_qe[kKD];
  const int tid = threadIdx.x;
  const int q = blockIdx.x;  // 0..2000
  if (tid < kKD) s_qe[tid] = q_embed_w[q * kKD + tid];
  __syncthreads();
  {
    float s = -1e30f;
    if (tid < kMem) {
      s = 0.f;
      for (int j = 0; j < kKD; ++j) s = fmaf(s_qe[j], Mk[tid * kKD + j], s);
    }
    float mx = s;
#pragma unroll
    for (int o = 1; o < 64; o <<= 1) mx = fmaxf(mx, __shfl_xor(mx, o));
    const float ev = (tid < kMem) ? expf(s - mx) : 0.f;
    float sm = ev;
#pragma unroll
    for (int o = 1; o < 64; o <<= 1) sm += __shfl_xor(sm, o);
    if (tid < kMem) ws[OFF_CW + (size_t)q * kMem + tid] = ev / sm;
  }
  if (tid < kFC) {
    float s = bs[tid];
    for (int j = 0; j < kKD; ++j) s = fmaf(s_qe[j], Ws[tid * 250 + kD + j], s);
    ws[OFF_SQ + (size_t)q * kFC + tid] = s;
  }
  if (tid < 4) {
    float v = 0.f;
    if (tid < 3) {
      float s = bbeta[tid];
      for (int j = 0; j < kKD; ++j) s = fmaf(s_qe[j], Wbeta[tid * kKD + j], s);
      v = tanhf(s);
    }
    ws[OFF_BQ + (size_t)q * 4 + tid] = v;
  }
  if (tid == 0) {
    float s = 0.f;
    for (int j = 0; j < kKD; ++j) s = fmaf(s_qe[j], Wdisc[kFC + j], s);
    ws[OFF_DQ + q] = s;
  }
}

// ---------------- main recurrent kernel ----------------
__device__ __forceinline__ void do_finale(int l, float wth_f, float wds_f, float bth0,
                                          float bdisc0, const float (*s_part)[64],
                                          const float* s_sq_row, const float* s_bqdq_row,
                                          float* out_ptr) {
  float summ = 0.f;
  if (l < kFC) {
    const float sp = s_part[0][l] + s_part[1][l] + s_part[2][l] + s_part[3][l] +
                     s_part[4][l] + s_sq_row[l];
    summ = fast_tanh(sp);
  }
  float p1 = wth_f * summ;
  float p2 = wds_f * summ;
#pragma unroll
  for (int o = 1; o < 64; o <<= 1) {
    p1 += __shfl_xor(p1, o);
    p2 += __shfl_xor(p2, o);
  }
  if (l == 0) {
    const float theta = 3.f * (p1 + bth0);
    const float alpha = fast_softplus(p2 + s_bqdq_row[3] + bdisc0);
    const float c1 = alpha * (theta - s_bqdq_row[0]);
    const float c2 = c1 + alpha * (theta - s_bqdq_row[1]);
    const float c3 = c2 + alpha * (theta - s_bqdq_row[2]);
    const float mx = fmaxf(fmaxf(0.f, c1), fmaxf(c2, c3));
    const float x0 = __expf(0.f - mx);
    const float x1 = __expf(c1 - mx);
    const float x2 = __expf(c2 - mx);
    const float x3 = __expf(c3 - mx);
    const float inv = 1.f / (x0 + x1 + x2 + x3);
    float4 pr;
    pr.x = x0 * inv;
    pr.y = x1 * inv;
    pr.z = x2 * inv;
    pr.w = x3 * inv;
    *reinterpret_cast<float4*>(out_ptr) = pr;
  }
}

__launch_bounds__(512, 4)
__global__ void dkvmn_main(const int* __restrict__ q_data, const int* __restrict__ r_data,
                           const float* __restrict__ Mv0, const float* __restrict__ Ws,
                           const float* __restrict__ Wth, const float* __restrict__ bth,
                           const float* __restrict__ Wdisc, const float* __restrict__ bdisc,
                           const float* __restrict__ ws, float* __restrict__ out) {
  const int tid = threadIdx.x;
  const int b = blockIdx.x;
  const int lane = tid & 63;
  const int wid = tid >> 6;
  const float* EAD = ws + OFF_EAD;
  const float* CW = ws + OFF_CW;
  const float* SQ = ws + OFF_SQ;
  const float* BQ = ws + OFF_BQ;
  const float* DQ = ws + OFF_DQ;

  __shared__ __align__(16) _Float16 s_wsh[kFC * kWP];   // f16 Ws(:,0:200) [f][d], pitch 216
  __shared__ __align__(16) _Float16 s_readh[2][2][208]; // [buf][half][d] f16 partial reads
  __shared__ __align__(16) float s_cw[2][64];
  __shared__ float s_part[2][5][64];
  __shared__ float s_sq[3][52];
  __shared__ float s_bqdq[3][4];
  __shared__ int s_q[kS];
  __shared__ int s_qr[kS];

  for (int e = tid; e < kFC * kD; e += 512) {
    const int f = e / kD;
    const int dd = e - f * kD;
    s_wsh[f * kWP + dd] = (_Float16)Ws[f * 250 + dd];
  }
  {
    const int* qrow = q_data + (size_t)b * kS;
    const int* rrow = r_data + (size_t)b * kS;
    for (int e = tid; e < kS; e += 512) {
      const int qv = qrow[e];
      s_q[e] = qv;
      s_qr[e] = (qv - 1) * 4 + rrow[e];
    }
  }
  // ---- role mapping ----
  // dact: tid in [112,512): u = tid-112; half1 = u>=200; d = u - (half1?200:0)
  //   half0 owns pairs 0..12 (mem slots 0..25); half1 owns pairs 13..24 (slots 26..49)
  // phase2: tid in [262,512): idx = tid-262 -> (pc, pf)
  // finale + cw staging: wave0.  sq staging: wave1 lanes<54.
  const bool dact = (tid >= 112);
  const int u = tid - 112;
  const bool half1 = (u >= 200);
  const int d = half1 ? (u - 200) : u;
  const int p0 = half1 ? 13 : 0;

  const bool pact = (tid >= 262);
  const int pidx = tid - 262;
  const int pc = pidx / 50;
  const int pf = pidx - pc * 50;

  f32x2 mv[13];
#pragma unroll
  for (int j = 0; j < 13; ++j) mv[j] = f32x2{0.f, 0.f};
  if (dact) {
#pragma unroll
    for (int j = 0; j < 12; ++j) {
      const int m2 = 2 * (p0 + j);
      mv[j][0] = Mv0[m2 * kD + d];
      mv[j][1] = Mv0[(m2 + 1) * kD + d];
    }
    if (!half1) {
      mv[12][0] = Mv0[24 * kD + d];
      mv[12][1] = Mv0[25 * kD + d];
    }
  }
  float wth_f = 0.f, wds_f = 0.f;
  if (wid == 0 && lane < kFC) {
    wth_f = Wth[lane];
    wds_f = Wdisc[lane];
  }
  const float bth0 = bth[0];
  const float bdisc0 = bdisc[0];
  float* out_b = out + (size_t)b * kS * 4;
  __syncthreads();  // init fills visible

  // prologue: stage step-0 consumables + register prefetch
  const int q0 = s_q[0];
  const int q1 = s_q[1];
  float2 ea_cur = make_float2(0.f, 0.f);
  if (dact) ea_cur = *(reinterpret_cast<const float2*>(EAD) + (s_qr[0] * kD + d));
  float cw_cur = 0.f;
  if (wid == 0 && lane < kMem) {
    s_cw[0][lane] = CW[q0 * kMem + lane];
    cw_cur = CW[q1 * kMem + lane];
  }
  float v2_cur = 0.f;
  if (wid == 1) {
    if (lane < kFC) v2_cur = SQ[q0 * kFC + lane];
    else if (lane < 53) v2_cur = BQ[q0 * 4 + (lane - 50)];
    else if (lane == 53) v2_cur = DQ[q0];
  }
  __syncthreads();  // s_cw[0] visible

  int i3 = 0;  // t % 3
  for (int t = 0; t < kS; ++t) {
    const int pb = t & 1;
    const int ip1 = (i3 + 1 < 3) ? i3 + 1 : 0;  // (t+1)%3 == (t-2)%3
    const int tn1 = (t + 1 < kS) ? t + 1 : kS - 1;
    const int tn2 = (t + 2 < kS) ? t + 2 : kS - 1;
    // ---- prefetch + staging ----
    f32x2 en2 = {0.f, 0.f}, ad2 = {0.f, 0.f};
    float2 ea_nxt = ea_cur;
    if (dact) {
      ea_nxt = *(reinterpret_cast<const float2*>(EAD) + (s_qr[tn1] * kD + d));
      en2[0] = -ea_cur.x;
      en2[1] = -ea_cur.x;
      ad2[0] = ea_cur.y;
      ad2[1] = ea_cur.y;
    }
    if (wid == 0 && lane < kMem) {  // cw for step t+1; prefetch t+2
      s_cw[pb ^ 1][lane] = cw_cur;
      cw_cur = CW[s_q[tn2] * kMem + lane];
    }
    if (wid == 1) {  // head inputs for step t (finale consumes at t+2); prefetch t+1
      const int qn = s_q[tn1];
      if (lane < kFC) {
        s_sq[i3][lane] = v2_cur;
        v2_cur = SQ[qn * kFC + lane];
      } else if (lane < 53) {
        s_bqdq[i3][lane - 50] = v2_cur;
        v2_cur = BQ[qn * 4 + (lane - 50)];
      } else if (lane == 53) {
        s_bqdq[i3][3] = v2_cur;
        v2_cur = DQ[qn];
      }
    }
    // ---- phase 1: Mv update + partial read (consumes s_cw[pb]) ----
    if (dact) {
      f32x2 r2a = {0.f, 0.f}, r2b = {0.f, 0.f};
      const f32x2* cw2 = reinterpret_cast<const f32x2*>(s_cw[pb]) + p0;
#pragma unroll
      for (int j = 0; j < 12; ++j) {
        const f32x2 c2 = cw2[j];
        if (j & 1) {
          r2b = pk_fma(c2, mv[j], r2b);
        } else {
          r2a = pk_fma(c2, mv[j], r2a);
        }
        mv[j] = pk_fma(c2, pk_fma(mv[j], en2, ad2), mv[j]);
      }
      if (!half1) {
        const f32x2 c2 = cw2[12];
        r2a = pk_fma(c2, mv[12], r2a);
        mv[12] = pk_fma(c2, pk_fma(mv[12], en2, ad2), mv[12]);
      }
      s_readh[pb][half1][d] = (_Float16)((r2a[0] + r2b[0]) + (r2a[1] + r2b[1]));
    }
    // ---- finale for step t-2 (wave0) ----
    if (wid == 0 && t >= 2) {
      do_finale(lane, wth_f, wds_f, bth0, bdisc0, s_part[pb ^ 1], s_sq[ip1], s_bqdq[ip1],
                out_b + (size_t)(t - 2) * 4);
    }
    // ---- phase 2: summary partials from read[t-1] ----
    if (pact) {
      const float4* wp = reinterpret_cast<const float4*>(s_wsh + pf * kWP + pc * 40);
      const float4* rpA = reinterpret_cast<const float4*>(&s_readh[pb ^ 1][0][pc * 40]);
      const float4* rpB = reinterpret_cast<const float4*>(&s_readh[pb ^ 1][1][pc * 40]);
      float acc0 = 0.f, acc1 = 0.f;
#pragma unroll
      for (int g = 0; g < 5; ++g) {
        const float4 wv = wp[g];
        const float4 va = rpA[g];
        const float4 vb = rpB[g];
        const h2_t r0 = __builtin_bit_cast(h2_t, va.x) + __builtin_bit_cast(h2_t, vb.x);
        const h2_t r1 = __builtin_bit_cast(h2_t, va.y) + __builtin_bit_cast(h2_t, vb.y);
        const h2_t r2 = __builtin_bit_cast(h2_t, va.z) + __builtin_bit_cast(h2_t, vb.z);
        const h2_t r3 = __builtin_bit_cast(h2_t, va.w) + __builtin_bit_cast(h2_t, vb.w);
        acc0 = __builtin_amdgcn_fdot2(__builtin_bit_cast(h2_t, wv.x), r0, acc0, false);
        acc1 = __builtin_amdgcn_fdot2(__builtin_bit_cast(h2_t, wv.y), r1, acc1, false);
        acc0 = __builtin_amdgcn_fdot2(__builtin_bit_cast(h2_t, wv.z), r2, acc0, false);
        acc1 = __builtin_amdgcn_fdot2(__builtin_bit_cast(h2_t, wv.w), r3, acc1, false);
      }
      s_part[pb][pc][pf] = acc0 + acc1;
    }
    lds_barrier();  // single per-step barrier
    ea_cur = ea_nxt;
    i3 = ip1;
  }
  // ---- epilogue: drain 2-deep pipeline (steps kS-2, kS-1) ----
  {
    constexpr int pbE = kS & 1;        // 0 for kS=500
    constexpr int i3a = (kS - 2) % 3;
    constexpr int i3b = (kS - 1) % 3;
    if (pact) {  // partials from read[kS-1] (in s_readh[(kS-1)&1])
      const float4* wp = reinterpret_cast<const float4*>(s_wsh + pf * kWP + pc * 40);
      const float4* rpA = reinterpret_cast<const float4*>(&s_readh[(kS - 1) & 1][0][pc * 40]);
      const float4* rpB = reinterpret_cast<const float4*>(&s_readh[(kS - 1) & 1][1][pc * 40]);
      float acc0 = 0.f, acc1 = 0.f;
#pragma unroll
      for (int g = 0; g < 5; ++g) {
        const float4 wv = wp[g];
        const float4 va = rpA[g];
        const float4 vb = rpB[g];
        const h2_t r0 = __builtin_bit_cast(h2_t, va.x) + __builtin_bit_cast(h2_t, vb.x);
        const h2_t r1 = __builtin_bit_cast(h2_t, va.y) + __builtin_bit_cast(h2_t, vb.y);
        const h2_t r2 = __builtin_bit_cast(h2_t, va.z) + __builtin_bit_cast(h2_t, vb.z);
        const h2_t r3 = __builtin_bit_cast(h2_t, va.w) + __builtin_bit_cast(h2_t, vb.w);
        acc0 = __builtin_amdgcn_fdot2(__builtin_bit_cast(h2_t, wv.x), r0, acc0, false);
        acc1 = __builtin_amdgcn_fdot2(__builtin_bit_cast(h2_t, wv.y), r1, acc1, false);
        acc0 = __builtin_amdgcn_fdot2(__builtin_bit_cast(h2_t, wv.z), r2, acc0, false);
        acc1 = __builtin_amdgcn_fdot2(__builtin_bit_cast(h2_t, wv.w), r3, acc1, false);
      }
      s_part[pbE][pc][pf] = acc0 + acc1;
    }
    if (wid == 0) {  // finale for step kS-2 (partials written at t=kS-1)
      do_finale(lane, wth_f, wds_f, bth0, bdisc0, s_part[pbE ^ 1], s_sq[i3a], s_bqdq[i3a],
                out_b + (size_t)(kS - 2) * 4);
    }
    lds_barrier();
    if (wid == 0) {  // finale for step kS-1
      do_finale(lane, wth_f, wds_f, bth0, bdisc0, s_part[pbE], s_sq[i3b], s_bqdq[i3b],
                out_b + (size_t)(kS - 1) * 4);
    }
  }
}

extern "C" void kernel_launch(void* const* d_in, const int* in_sizes, int n_in,
                              void* d_out, int out_size, void* d_ws, size_t ws_size,
                              hipStream_t stream) {
  (void)in_sizes; (void)n_in; (void)out_size; (void)ws_size;
  const int* q_data = (const int*)d_in[0];
  const int* r_data = (const int*)d_in[1];
  const float* q_embed_w = (const float*)d_in[2];
  const float* Mk = (const float*)d_in[3];
  const float* Mv0 = (const float*)d_in[4];
  const float* Wv = (const float*)d_in[5];
  const float* bv = (const float*)d_in[6];
  const float* We = (const float*)d_in[7];
  const float* be = (const float*)d_in[8];
  const float* Wa = (const float*)d_in[9];
  const float* ba = (const float*)d_in[10];
  const float* Ws = (const float*)d_in[11];
  const float* bs = (const float*)d_in[12];
  const float* Wth = (const float*)d_in[13];
  const float* bth = (const float*)d_in[14];
  const float* Wbeta = (const float*)d_in[15];
  const float* bbeta = (const float*)d_in[16];
  const float* Wdisc = (const float*)d_in[17];
  const float* bdisc = (const float*)d_in[18];
  float* out = (float*)d_out;
  float* ws = (float*)d_ws;

  hipLaunchKernelGGL(prep1_misc, dim3(64), dim3(256), 0, stream, We, Wa, bv, be, ba, ws);
  hipLaunchKernelGGL(prep2_ead, dim3(kQ), dim3(256), 0, stream, Wv, ws);
  hipLaunchKernelGGL(prep3_qtables, dim3(kQ + 1), dim3(64), 0, stream, q_embed_w, Mk, Ws, bs,
                     Wbeta, bbeta, Wdisc, ws);
  hipLaunchKernelGGL(dkvmn_main, dim3(kB), dim3(512), 0, stream, q_data, r_data, Mv0, Ws, Wth,
                     bth, Wdisc, bdisc, ws, out);
}

// Round 9
// 1265.803 us; speedup vs baseline: 1.5530x; 1.1661x over previous
//
#include <hip/hip_runtime.h>
#include <hip/hip_bf16.h>
#include <cstdint>
#include <cstddef>

// DeepGPCM / DKVMN recurrence.
//  - erase/add are pure functions of (q,r): precomputed table EAD[(q-1)*4+r][d] = {erase,add}.
//  - attention softmax pure function of q: precomputed CW[q][50].
//  - per-question tables SQ (Ws_q*qe+bs), BQ (tanh betas), DQ (Wdisc_q*qe).
//  - main kernel (R6 structure, best so far): 256 threads, 1 block / batch element,
//    Mv[50] in register pairs (v_pk_fma_f32), single lds-only barrier per step, all LDS
//    buffers cross-step double/triple-buffered, finale deferred 2 steps.
//  - NEW: time loop unrolled 6x (lcm of the mod-2 and mod-3 buffer indices) so every LDS
//    buffer index is a compile-time constant; min-clamps drop out of the main loop
//    (t<=497 -> t+2<=499 in-range); tail steps t=498,499 written out with static indices.
//    This removes the ~2.5x dynamic-indexing/bookkeeping VALU overhead seen in R6.

namespace {
constexpr int kB   = 1024;
constexpr int kS   = 500;
constexpr int kQ   = 2000;
constexpr int kKD  = 50;
constexpr int kMem = 50;
constexpr int kD   = 200;
constexpr int kFC  = 50;
constexpr int kWP  = 216;  // f16 pitch for s_wsh rows

// ws layout in floats
constexpr size_t OFF_EAD  = 0;                              // 2000*4*200*2 = 3,200,000
constexpr size_t OFF_CW   = OFF_EAD + (size_t)kQ * 4 * kD * 2;
constexpr size_t OFF_SQ   = OFF_CW + 100064;                // CW: 2001*50
constexpr size_t OFF_BQ   = OFF_SQ + 100064;                // SQ: 2001*50
constexpr size_t OFF_DQ   = OFF_BQ + 8032;                  // BQ: 2001*4
constexpr size_t OFF_CE   = OFF_DQ + 2016;                  // DQ: 2001
constexpr size_t OFF_CA   = OFF_CE + 224;
constexpr size_t OFF_WET  = OFF_CA + 224;
constexpr size_t OFF_WAT  = OFF_WET + 40000;
}  // namespace

typedef float f32x2 __attribute__((ext_vector_type(2)));
typedef _Float16 h2_t __attribute__((ext_vector_type(2)));

__device__ __forceinline__ f32x2 pk_fma(f32x2 a, f32x2 b, f32x2 c) {
  f32x2 d;
  asm("v_pk_fma_f32 %0, %1, %2, %3" : "=v"(d) : "v"(a), "v"(b), "v"(c));
  return d;
}

__device__ __forceinline__ void lds_barrier() {
  asm volatile("s_waitcnt lgkmcnt(0)" ::: "memory");
  __builtin_amdgcn_s_barrier();
  asm volatile("" ::: "memory");
}

__device__ __forceinline__ float fast_tanh(float x) {
  const float ax = fabsf(x);
  const float t = __expf(-2.f * ax);
  const float r = (1.f - t) / (1.f + t);
  return copysignf(r, x);
}
__device__ __forceinline__ float fast_softplus(float x) {
  return fmaxf(x, 0.f) + log1pf(__expf(-fabsf(x)));
}

// ---------------- prep 1: transposes + bias folds ----------------
__global__ void prep1_misc(const float* __restrict__ We, const float* __restrict__ Wa,
                           const float* __restrict__ bv, const float* __restrict__ be,
                           const float* __restrict__ ba, float* __restrict__ ws) {
  float* WeT = ws + OFF_WET;
  float* WaT = ws + OFF_WAT;
  float* ce  = ws + OFF_CE;
  float* ca  = ws + OFF_CA;
  const int gt = blockIdx.x * 256 + threadIdx.x;
  const int stride = gridDim.x * 256;
  for (int e = gt; e < kD * kD; e += stride) {
    const int i = e / kD;
    const int dd = e - i * kD;
    WeT[e] = We[dd * kD + i];
    WaT[e] = Wa[dd * kD + i];
  }
  for (int dd = gt; dd < kD; dd += stride) {
    float acc_e = be[dd], acc_a = ba[dd];
    for (int i = 0; i < kD; ++i) {
      acc_e = fmaf(We[dd * kD + i], bv[i], acc_e);
      acc_a = fmaf(Wa[dd * kD + i], bv[i], acc_a);
    }
    ce[dd] = acc_e;
    ca[dd] = acc_a;
  }
}

// ---------------- prep 2: EAD table = {sigmoid(We@ve+be), tanh(Wa@ve+ba)} per (q,r,d) ----
__global__ void prep2_ead(const float* __restrict__ Wv, float* __restrict__ ws) {
  __shared__ float s_wv[4][kD];
  const int tid = threadIdx.x;
  const int qm1 = blockIdx.x;  // question-1 in [0,2000)
  for (int e = tid; e < 4 * kD; e += 256) {
    const int k = e / kD;
    const int i = e - k * kD;
    s_wv[k][i] = Wv[(size_t)i * (4 * kQ) + (size_t)k * kQ + qm1];
  }
  __syncthreads();
  const int d = tid;
  if (d < kD) {
    const float* WeT = ws + OFF_WET;
    const float* WaT = ws + OFF_WAT;
    float e0 = 0.f, e1 = 0.f, e2 = 0.f, e3 = 0.f;
    float a0 = 0.f, a1 = 0.f, a2 = 0.f, a3 = 0.f;
    for (int i = 0; i < kD; ++i) {
      const float we = WeT[i * kD + d];
      const float wa = WaT[i * kD + d];
      e0 = fmaf(we, s_wv[0][i], e0);
      e1 = fmaf(we, s_wv[1][i], e1);
      e2 = fmaf(we, s_wv[2][i], e2);
      e3 = fmaf(we, s_wv[3][i], e3);
      a0 = fmaf(wa, s_wv[0][i], a0);
      a1 = fmaf(wa, s_wv[1][i], a1);
      a2 = fmaf(wa, s_wv[2][i], a2);
      a3 = fmaf(wa, s_wv[3][i], a3);
    }
    const float ced = ws[OFF_CE + d];
    const float cad = ws[OFF_CA + d];
    const float W[4][4] = {{1.f, 2.f / 3.f, 1.f / 3.f, 0.f},
                           {2.f / 3.f, 1.f, 2.f / 3.f, 1.f / 3.f},
                           {1.f / 3.f, 2.f / 3.f, 1.f, 2.f / 3.f},
                           {0.f, 1.f / 3.f, 2.f / 3.f, 1.f}};
#pragma unroll
    for (int r = 0; r < 4; ++r) {
      const float ep = ced + W[r][0] * e0 + W[r][1] * e1 + W[r][2] * e2 + W[r][3] * e3;
      const float ap = cad + W[r][0] * a0 + W[r][1] * a1 + W[r][2] * a2 + W[r][3] * a3;
      float2 v;
      v.x = 1.f / (1.f + expf(-ep));  // erase
      v.y = tanhf(ap);                // add
      *reinterpret_cast<float2*>(ws + OFF_EAD + ((size_t)(qm1 * 4 + r) * kD + d) * 2) = v;
    }
  }
}

// ---------------- prep 3: per-question tables CW/SQ/BQ/DQ ----------------
__global__ void prep3_qtables(const float* __restrict__ q_embed_w, const float* __restrict__ Mk,
                              const float* __restrict__ Ws, const float* __restrict__ bs,
                              const float* __restrict__ Wbeta, const float* __restrict__ bbeta,
                              const float* __restrict__ Wdisc, float* __restrict__ ws) {
  __shared__ float s_qe[kKD];
  const int tid = threadIdx.x;
  const int q = blockIdx.x;  // 0..2000
  if (tid < kKD) s_qe[tid] = q_embed_w[q * kKD + tid];
  __syncthreads();
  {
    float s = -1e30f;
    if (tid < kMem) {
      s = 0.f;
      for (int j = 0; j < kKD; ++j) s = fmaf(s_qe[j], Mk[tid * kKD + j], s);
    }
    float mx = s;
#pragma unroll
    for (int o = 1; o < 64; o <<= 1) mx = fmaxf(mx, __shfl_xor(mx, o));
    const float ev = (tid < kMem) ? expf(s - mx) : 0.f;
    float sm = ev;
#pragma unroll
    for (int o = 1; o < 64; o <<= 1) sm += __shfl_xor(sm, o);
    if (tid < kMem) ws[OFF_CW + (size_t)q * kMem + tid] = ev / sm;
  }
  if (tid < kFC) {
    float s = bs[tid];
    for (int j = 0; j < kKD; ++j) s = fmaf(s_qe[j], Ws[tid * 250 + kD + j], s);
    ws[OFF_SQ + (size_t)q * kFC + tid] = s;
  }
  if (tid < 4) {
    float v = 0.f;
    if (tid < 3) {
      float s = bbeta[tid];
      for (int j = 0; j < kKD; ++j) s = fmaf(s_qe[j], Wbeta[tid * kKD + j], s);
      v = tanhf(s);
    }
    ws[OFF_BQ + (size_t)q * 4 + tid] = v;
  }
  if (tid == 0) {
    float s = 0.f;
    for (int j = 0; j < kKD; ++j) s = fmaf(s_qe[j], Wdisc[kFC + j], s);
    ws[OFF_DQ + q] = s;
  }
}

// ---------------- main recurrent kernel ----------------
__device__ __forceinline__ void do_finale(int l, float wth_f, float wds_f, float bth0,
                                          float bdisc0, const float (*s_part)[64],
                                          const float* s_sq_row, const float* s_bqdq_row,
                                          float* out_ptr) {
  float summ = 0.f;
  if (l < kFC) {
    const float sp = s_part[0][l] + s_part[1][l] + s_part[2][l] + s_part[3][l] +
                     s_part[4][l] + s_sq_row[l];
    summ = fast_tanh(sp);
  }
  float p1 = wth_f * summ;
  float p2 = wds_f * summ;
#pragma unroll
  for (int o = 1; o < 64; o <<= 1) {
    p1 += __shfl_xor(p1, o);
    p2 += __shfl_xor(p2, o);
  }
  if (l == 0) {
    const float theta = 3.f * (p1 + bth0);
    const float alpha = fast_softplus(p2 + s_bqdq_row[3] + bdisc0);
    const float c1 = alpha * (theta - s_bqdq_row[0]);
    const float c2 = c1 + alpha * (theta - s_bqdq_row[1]);
    const float c3 = c2 + alpha * (theta - s_bqdq_row[2]);
    const float mx = fmaxf(fmaxf(0.f, c1), fmaxf(c2, c3));
    const float x0 = __expf(0.f - mx);
    const float x1 = __expf(c1 - mx);
    const float x2 = __expf(c2 - mx);
    const float x3 = __expf(c3 - mx);
    const float inv = 1.f / (x0 + x1 + x2 + x3);
    float4 pr;
    pr.x = x0 * inv;
    pr.y = x1 * inv;
    pr.z = x2 * inv;
    pr.w = x3 * inv;
    *reinterpret_cast<float4*>(out_ptr) = pr;
  }
}

// One time-step with COMPILE-TIME buffer indices PB (= t&1) and I3 (= t%3).
// T, TN1, TN2 are runtime ints (TN1/TN2 pre-clamped by the caller).
#define STEP(PB, I3, T, TN1, TN2)                                                     \
  {                                                                                   \
    constexpr int IP1_ = ((I3) + 1) % 3;                                              \
    f32x2 en2 = {0.f, 0.f}, ad2 = {0.f, 0.f};                                         \
    float2 ea_nxt = ea_cur;                                                           \
    if (dact) {                                                                       \
      ea_nxt = EAD2[(size_t)s_qr[(TN1)] * kD + d];                                    \
      en2[0] = -ea_cur.x;                                                             \
      en2[1] = -ea_cur.x;                                                             \
      ad2[0] = ea_cur.y;                                                              \
      ad2[1] = ea_cur.y;                                                              \
    }                                                                                 \
    if (wid == 0 && lane < kMem) { /* cw for step T+1; prefetch T+2 */                \
      s_cw[(PB) ^ 1][lane] = cw_cur;                                                  \
      cw_cur = CW[s_q[(TN2)] * kMem + lane];                                          \
    }                                                                                 \
    if (wid == 1) { /* head inputs for step T (finale at T+2); prefetch T+1 */        \
      const int qn_ = s_q[(TN1)];                                                     \
      if (lane < kFC) {                                                               \
        s_sq[(I3)][lane] = v2_cur;                                                    \
        v2_cur = SQ[qn_ * kFC + lane];                                                \
      } else if (lane < 53) {                                                         \
        s_bqdq[(I3)][lane - 50] = v2_cur;                                             \
        v2_cur = BQ[qn_ * 4 + (lane - 50)];                                           \
      } else if (lane == 53) {                                                        \
        s_bqdq[(I3)][3] = v2_cur;                                                     \
        v2_cur = DQ[qn_];                                                             \
      }                                                                               \
    }                                                                                 \
    if (dact) { /* phase 1: Mv update + read (consumes s_cw[PB]) */                   \
      f32x2 r2a = {0.f, 0.f}, r2b = {0.f, 0.f};                                       \
      const float4* cw4_ = reinterpret_cast<const float4*>(s_cw[(PB)]);               \
      _Pragma("unroll") for (int g = 0; g < 12; ++g) {                                \
        const float4 c4_ = cw4_[g];                                                   \
        const f32x2 clo_ = {c4_.x, c4_.y};                                            \
        const f32x2 chi_ = {c4_.z, c4_.w};                                            \
        r2a = pk_fma(clo_, mv[2 * g], r2a);                                           \
        mv[2 * g] = pk_fma(clo_, pk_fma(mv[2 * g], en2, ad2), mv[2 * g]);             \
        r2b = pk_fma(chi_, mv[2 * g + 1], r2b);                                       \
        mv[2 * g + 1] = pk_fma(chi_, pk_fma(mv[2 * g + 1], en2, ad2), mv[2 * g + 1]); \
      }                                                                               \
      {                                                                               \
        const f32x2 cl_ = *reinterpret_cast<const f32x2*>(&s_cw[(PB)][48]);           \
        r2a = pk_fma(cl_, mv[24], r2a);                                               \
        mv[24] = pk_fma(cl_, pk_fma(mv[24], en2, ad2), mv[24]);                       \
      }                                                                               \
      s_readh[(PB)][d] = (_Float16)((r2a[0] + r2b[0]) + (r2a[1] + r2b[1]));           \
    }                                                                                 \
    if (wid == 0 && (T) >= 2) { /* finale for step T-2 */                             \
      do_finale(lane, wth_f, wds_f, bth0, bdisc0, s_part[(PB) ^ 1], s_sq[IP1_],       \
                s_bqdq[IP1_], out_b + (size_t)((T) - 2) * 4);                         \
    }                                                                                 \
    if (tid < 250) { /* phase 2: summary partials from read[T-1] */                   \
      const float4* wp_ = reinterpret_cast<const float4*>(s_wsh + pf * kWP + pc * 40);\
      const float4* rp_ = reinterpret_cast<const float4*>(&s_readh[(PB) ^ 1][pc * 40]);\
      float a0_ = 0.f, a1_ = 0.f;                                                     \
      _Pragma("unroll") for (int g = 0; g < 5; ++g) {                                 \
        const float4 wv_ = wp_[g];                                                    \
        const float4 rv_ = rp_[g];                                                    \
        a0_ = __builtin_amdgcn_fdot2(__builtin_bit_cast(h2_t, wv_.x),                 \
                                     __builtin_bit_cast(h2_t, rv_.x), a0_, false);    \
        a1_ = __builtin_amdgcn_fdot2(__builtin_bit_cast(h2_t, wv_.y),                 \
                                     __builtin_bit_cast(h2_t, rv_.y), a1_, false);    \
        a0_ = __builtin_amdgcn_fdot2(__builtin_bit_cast(h2_t, wv_.z),                 \
                                     __builtin_bit_cast(h2_t, rv_.z), a0_, false);    \
        a1_ = __builtin_amdgcn_fdot2(__builtin_bit_cast(h2_t, wv_.w),                 \
                                     __builtin_bit_cast(h2_t, rv_.w), a1_, false);    \
      }                                                                               \
      s_part[(PB)][pc][pf] = a0_ + a1_;                                               \
    }                                                                                 \
    lds_barrier(); /* single per-step barrier */                                      \
    ea_cur = ea_nxt;                                                                  \
  }

__launch_bounds__(256, 4)
__global__ void dkvmn_main(const int* __restrict__ q_data, const int* __restrict__ r_data,
                           const float* __restrict__ Mv0, const float* __restrict__ Ws,
                           const float* __restrict__ Wth, const float* __restrict__ bth,
                           const float* __restrict__ Wdisc, const float* __restrict__ bdisc,
                           const float* __restrict__ ws, float* __restrict__ out) {
  const int tid = threadIdx.x;
  const int b = blockIdx.x;
  const int lane = tid & 63;
  const int wid = tid >> 6;
  const float2* EAD2 = reinterpret_cast<const float2*>(ws + OFF_EAD);
  const float* CW = ws + OFF_CW;
  const float* SQ = ws + OFF_SQ;
  const float* BQ = ws + OFF_BQ;
  const float* DQ = ws + OFF_DQ;

  __shared__ __align__(16) _Float16 s_wsh[kFC * kWP];  // f16 Ws(:,0:200) [f][d], pitch 216
  __shared__ __align__(16) _Float16 s_readh[2][208];   // f16 read vector, double-buffered
  __shared__ __align__(16) float s_cw[2][64];
  __shared__ float s_part[2][5][64];
  __shared__ float s_sq[3][52];
  __shared__ float s_bqdq[3][4];
  __shared__ int s_q[kS];
  __shared__ int s_qr[kS];

  for (int e = tid; e < kFC * kD; e += 256) {
    const int f = e / kD;
    const int dd = e - f * kD;
    s_wsh[f * kWP + dd] = (_Float16)Ws[f * 250 + dd];
  }
  {
    const int* qrow = q_data + (size_t)b * kS;
    const int* rrow = r_data + (size_t)b * kS;
    for (int e = tid; e < kS; e += 256) {
      const int qv = qrow[e];
      s_q[e] = qv;
      s_qr[e] = (qv - 1) * 4 + rrow[e];
    }
  }
  const int d = tid;
  const bool dact = (d < kD);
  const int pc = tid / 50;          // phase-2 mapping (valid for tid<250)
  const int pf = tid - pc * 50;
  f32x2 mv[25];
#pragma unroll
  for (int m = 0; m < 25; ++m) mv[m] = f32x2{0.f, 0.f};
  if (dact) {
#pragma unroll
    for (int m = 0; m < 25; ++m) {
      mv[m][0] = Mv0[(2 * m) * kD + d];
      mv[m][1] = Mv0[(2 * m + 1) * kD + d];
    }
  }
  float wth_f = 0.f, wds_f = 0.f;
  if (wid == 0 && lane < kFC) {
    wth_f = Wth[lane];
    wds_f = Wdisc[lane];
  }
  const float bth0 = bth[0];
  const float bdisc0 = bdisc[0];
  float* out_b = out + (size_t)b * kS * 4;
  __syncthreads();  // init fills visible

  // prologue: stage step-0 consumables + register prefetch for step 1
  const int q0 = s_q[0];
  const int q1 = s_q[1];
  float2 ea_cur = make_float2(0.f, 0.f);
  if (dact) ea_cur = EAD2[(size_t)s_qr[0] * kD + d];
  float cw_cur = 0.f;
  if (wid == 0 && lane < kMem) {
    s_cw[0][lane] = CW[q0 * kMem + lane];
    cw_cur = CW[q1 * kMem + lane];
  }
  float v2_cur = 0.f;
  if (wid == 1) {
    if (lane < kFC) v2_cur = SQ[q0 * kFC + lane];
    else if (lane < 53) v2_cur = BQ[q0 * 4 + (lane - 50)];
    else if (lane == 53) v2_cur = DQ[q0];
  }
  __syncthreads();  // s_cw[0] visible

  // main loop: 83 x unroll-6 covers t = 0..497; all mod-2/mod-3 indices compile-time.
  // For t <= 497: t+2 <= 499, so no clamps needed.
  for (int it = 0; it < 83; ++it) {
    const int t0 = 6 * it;
    STEP(0, 0, t0 + 0, t0 + 1, t0 + 2)
    STEP(1, 1, t0 + 1, t0 + 2, t0 + 3)
    STEP(0, 2, t0 + 2, t0 + 3, t0 + 4)
    STEP(1, 0, t0 + 3, t0 + 4, t0 + 5)
    STEP(0, 1, t0 + 4, t0 + 5, t0 + 6)
    STEP(1, 2, t0 + 5, t0 + 6, t0 + 7)
  }
  // tail: t = 498 (PB=0, I3=0), t = 499 (PB=1, I3=1); clamped lookahead.
  STEP(0, 0, 498, 499, 499)
  STEP(1, 1, 499, 499, 499)

  // ---- epilogue: drain 2-deep pipeline (steps 498, 499) ----
  {
    constexpr int pbE = kS & 1;        // 0
    constexpr int i3a = (kS - 2) % 3;  // 0
    constexpr int i3b = (kS - 1) % 3;  // 1
    if (tid < 250) {  // partials from read[499] (in s_readh[1])
      const float4* wp = reinterpret_cast<const float4*>(s_wsh + pf * kWP + pc * 40);
      const float4* rp = reinterpret_cast<const float4*>(&s_readh[(kS - 1) & 1][pc * 40]);
      float acc0 = 0.f, acc1 = 0.f;
#pragma unroll
      for (int g = 0; g < 5; ++g) {
        const float4 wv = wp[g];
        const float4 rv = rp[g];
        acc0 = __builtin_amdgcn_fdot2(__builtin_bit_cast(h2_t, wv.x),
                                      __builtin_bit_cast(h2_t, rv.x), acc0, false);
        acc1 = __builtin_amdgcn_fdot2(__builtin_bit_cast(h2_t, wv.y),
                                      __builtin_bit_cast(h2_t, rv.y), acc1, false);
        acc0 = __builtin_amdgcn_fdot2(__builtin_bit_cast(h2_t, wv.z),
                                      __builtin_bit_cast(h2_t, rv.z), acc0, false);
        acc1 = __builtin_amdgcn_fdot2(__builtin_bit_cast(h2_t, wv.w),
                                      __builtin_bit_cast(h2_t, rv.w), acc1, false);
      }
      s_part[pbE][pc][pf] = acc0 + acc1;
    }
    if (wid == 0) {  // finale for step 498 (partials written at t=499)
      do_finale(lane, wth_f, wds_f, bth0, bdisc0, s_part[pbE ^ 1], s_sq[i3a], s_bqdq[i3a],
                out_b + (size_t)(kS - 2) * 4);
    }
    lds_barrier();
    if (wid == 0) {  // finale for step 499
      do_finale(lane, wth_f, wds_f, bth0, bdisc0, s_part[pbE], s_sq[i3b], s_bqdq[i3b],
                out_b + (size_t)(kS - 1) * 4);
    }
  }
}

extern "C" void kernel_launch(void* const* d_in, const int* in_sizes, int n_in,
                              void* d_out, int out_size, void* d_ws, size_t ws_size,
                              hipStream_t stream) {
  (void)in_sizes; (void)n_in; (void)out_size; (void)ws_size;
  const int* q_data = (const int*)d_in[0];
  const int* r_data = (const int*)d_in[1];
  const float* q_embed_w = (const float*)d_in[2];
  const float* Mk = (const float*)d_in[3];
  const float* Mv0 = (const float*)d_in[4];
  const float* Wv = (const float*)d_in[5];
  const float* bv = (const float*)d_in[6];
  const float* We = (const float*)d_in[7];
  const float* be = (const float*)d_in[8];
  const float* Wa = (const float*)d_in[9];
  const float* ba = (const float*)d_in[10];
  const float* Ws = (const float*)d_in[11];
  const float* bs = (const float*)d_in[12];
  const float* Wth = (const float*)d_in[13];
  const float* bth = (const float*)d_in[14];
  const float* Wbeta = (const float*)d_in[15];
  const float* bbeta = (const float*)d_in[16];
  const float* Wdisc = (const float*)d_in[17];
  const float* bdisc = (const float*)d_in[18];
  float* out = (float*)d_out;
  float* ws = (float*)d_ws;

  hipLaunchKernelGGL(prep1_misc, dim3(64), dim3(256), 0, stream, We, Wa, bv, be, ba, ws);
  hipLaunchKernelGGL(prep2_ead, dim3(kQ), dim3(256), 0, stream, Wv, ws);
  hipLaunchKernelGGL(prep3_qtables, dim3(kQ + 1), dim3(64), 0, stream, q_embed_w, Mk, Ws, bs,
                     Wbeta, bbeta, Wdisc, ws);
  hipLaunchKernelGGL(dkvmn_main, dim3(kB), dim3(256), 0, stream, q_data, r_data, Mv0, Ws, Wth,
                     bth, Wdisc, bdisc, ws, out);
}

// Round 10
// 1119.499 us; speedup vs baseline: 1.7560x; 1.1307x over previous
//
#include <hip/hip_runtime.h>
#include <hip/hip_bf16.h>
#include <cstdint>
#include <cstddef>

// DeepGPCM / DKVMN recurrence, SPLIT into:
//   dkvmn_rec : the true recurrence (Mv update + read production). read[t] -> global f16.
//               cw 4-deep ring in LDS, ONE lds-only barrier per 2 steps, EAD/CW prefetch
//               2-4 steps deep. No phase2/finale in the coupled loop.
//   dkvmn_head: feed-forward summary GEMV + GPCM head over all 512000 (b,t) rows,
//               reusing the proven phase2/finale dataflow (fdot2 on f16).
// Requires R buffer (1024*500*200 f16 = 204.8 MB) in ws. If ws_size is too small,
// falls back to the proven R9 fused kernel (host-side branch on ws_size: constant
// across calls -> graph-capture safe).
// Tables (proven): EAD[(q-1)*4+r][d]={erase,add}, CW[q][50], SQ/BQ/DQ per question.

namespace {
constexpr int kB   = 1024;
constexpr int kS   = 500;
constexpr int kQ   = 2000;
constexpr int kKD  = 50;
constexpr int kMem = 50;
constexpr int kD   = 200;
constexpr int kFC  = 50;
constexpr int kWP  = 216;  // f16 pitch for s_wsh rows

// ws layout in floats
constexpr size_t OFF_EAD  = 0;                              // 2000*4*200*2 = 3,200,000
constexpr size_t OFF_CW   = OFF_EAD + (size_t)kQ * 4 * kD * 2;
constexpr size_t OFF_SQ   = OFF_CW + 100064;                // CW: 2001*50
constexpr size_t OFF_BQ   = OFF_SQ + 100064;                // SQ: 2001*50
constexpr size_t OFF_DQ   = OFF_BQ + 8032;                  // BQ: 2001*4
constexpr size_t OFF_CE   = OFF_DQ + 2016;                  // DQ: 2001
constexpr size_t OFF_CA   = OFF_CE + 224;
constexpr size_t OFF_WET  = OFF_CA + 224;
constexpr size_t OFF_WAT  = OFF_WET + 40000;
constexpr size_t OFF_R    = 3490816;                        // aligned past 3,490,624
constexpr size_t NEED_WS  = OFF_R * 4 + (size_t)kB * kS * kD * 2;  // ~218.8 MB
}  // namespace

typedef float f32x2 __attribute__((ext_vector_type(2)));
typedef _Float16 h2_t __attribute__((ext_vector_type(2)));

__device__ __forceinline__ f32x2 pk_fma(f32x2 a, f32x2 b, f32x2 c) {
  f32x2 d;
  asm("v_pk_fma_f32 %0, %1, %2, %3" : "=v"(d) : "v"(a), "v"(b), "v"(c));
  return d;
}

__device__ __forceinline__ void lds_barrier() {
  asm volatile("s_waitcnt lgkmcnt(0)" ::: "memory");
  __builtin_amdgcn_s_barrier();
  asm volatile("" ::: "memory");
}

__device__ __forceinline__ float fast_tanh(float x) {
  const float ax = fabsf(x);
  const float t = __expf(-2.f * ax);
  const float r = (1.f - t) / (1.f + t);
  return copysignf(r, x);
}
__device__ __forceinline__ float fast_softplus(float x) {
  return fmaxf(x, 0.f) + log1pf(__expf(-fabsf(x)));
}

// ---------------- prep 1: transposes + bias folds ----------------
__global__ void prep1_misc(const float* __restrict__ We, const float* __restrict__ Wa,
                           const float* __restrict__ bv, const float* __restrict__ be,
                           const float* __restrict__ ba, float* __restrict__ ws) {
  float* WeT = ws + OFF_WET;
  float* WaT = ws + OFF_WAT;
  float* ce  = ws + OFF_CE;
  float* ca  = ws + OFF_CA;
  const int gt = blockIdx.x * 256 + threadIdx.x;
  const int stride = gridDim.x * 256;
  for (int e = gt; e < kD * kD; e += stride) {
    const int i = e / kD;
    const int dd = e - i * kD;
    WeT[e] = We[dd * kD + i];
    WaT[e] = Wa[dd * kD + i];
  }
  for (int dd = gt; dd < kD; dd += stride) {
    float acc_e = be[dd], acc_a = ba[dd];
    for (int i = 0; i < kD; ++i) {
      acc_e = fmaf(We[dd * kD + i], bv[i], acc_e);
      acc_a = fmaf(Wa[dd * kD + i], bv[i], acc_a);
    }
    ce[dd] = acc_e;
    ca[dd] = acc_a;
  }
}

// ---------------- prep 2: EAD table = {sigmoid(We@ve+be), tanh(Wa@ve+ba)} per (q,r,d) ----
__global__ void prep2_ead(const float* __restrict__ Wv, float* __restrict__ ws) {
  __shared__ float s_wv[4][kD];
  const int tid = threadIdx.x;
  const int qm1 = blockIdx.x;  // question-1 in [0,2000)
  for (int e = tid; e < 4 * kD; e += 256) {
    const int k = e / kD;
    const int i = e - k * kD;
    s_wv[k][i] = Wv[(size_t)i * (4 * kQ) + (size_t)k * kQ + qm1];
  }
  __syncthreads();
  const int d = tid;
  if (d < kD) {
    const float* WeT = ws + OFF_WET;
    const float* WaT = ws + OFF_WAT;
    float e0 = 0.f, e1 = 0.f, e2 = 0.f, e3 = 0.f;
    float a0 = 0.f, a1 = 0.f, a2 = 0.f, a3 = 0.f;
    for (int i = 0; i < kD; ++i) {
      const float we = WeT[i * kD + d];
      const float wa = WaT[i * kD + d];
      e0 = fmaf(we, s_wv[0][i], e0);
      e1 = fmaf(we, s_wv[1][i], e1);
      e2 = fmaf(we, s_wv[2][i], e2);
      e3 = fmaf(we, s_wv[3][i], e3);
      a0 = fmaf(wa, s_wv[0][i], a0);
      a1 = fmaf(wa, s_wv[1][i], a1);
      a2 = fmaf(wa, s_wv[2][i], a2);
      a3 = fmaf(wa, s_wv[3][i], a3);
    }
    const float ced = ws[OFF_CE + d];
    const float cad = ws[OFF_CA + d];
    const float W[4][4] = {{1.f, 2.f / 3.f, 1.f / 3.f, 0.f},
                           {2.f / 3.f, 1.f, 2.f / 3.f, 1.f / 3.f},
                           {1.f / 3.f, 2.f / 3.f, 1.f, 2.f / 3.f},
                           {0.f, 1.f / 3.f, 2.f / 3.f, 1.f}};
#pragma unroll
    for (int r = 0; r < 4; ++r) {
      const float ep = ced + W[r][0] * e0 + W[r][1] * e1 + W[r][2] * e2 + W[r][3] * e3;
      const float ap = cad + W[r][0] * a0 + W[r][1] * a1 + W[r][2] * a2 + W[r][3] * a3;
      float2 v;
      v.x = 1.f / (1.f + expf(-ep));  // erase
      v.y = tanhf(ap);                // add
      *reinterpret_cast<float2*>(ws + OFF_EAD + ((size_t)(qm1 * 4 + r) * kD + d) * 2) = v;
    }
  }
}

// ---------------- prep 3: per-question tables CW/SQ/BQ/DQ ----------------
__global__ void prep3_qtables(const float* __restrict__ q_embed_w, const float* __restrict__ Mk,
                              const float* __restrict__ Ws, const float* __restrict__ bs,
                              const float* __restrict__ Wbeta, const float* __restrict__ bbeta,
                              const float* __restrict__ Wdisc, float* __restrict__ ws) {
  __shared__ float s_qe[kKD];
  const int tid = threadIdx.x;
  const int q = blockIdx.x;  // 0..2000
  if (tid < kKD) s_qe[tid] = q_embed_w[q * kKD + tid];
  __syncthreads();
  {
    float s = -1e30f;
    if (tid < kMem) {
      s = 0.f;
      for (int j = 0; j < kKD; ++j) s = fmaf(s_qe[j], Mk[tid * kKD + j], s);
    }
    float mx = s;
#pragma unroll
    for (int o = 1; o < 64; o <<= 1) mx = fmaxf(mx, __shfl_xor(mx, o));
    const float ev = (tid < kMem) ? expf(s - mx) : 0.f;
    float sm = ev;
#pragma unroll
    for (int o = 1; o < 64; o <<= 1) sm += __shfl_xor(sm, o);
    if (tid < kMem) ws[OFF_CW + (size_t)q * kMem + tid] = ev / sm;
  }
  if (tid < kFC) {
    float s = bs[tid];
    for (int j = 0; j < kKD; ++j) s = fmaf(s_qe[j], Ws[tid * 250 + kD + j], s);
    ws[OFF_SQ + (size_t)q * kFC + tid] = s;
  }
  if (tid < 4) {
    float v = 0.f;
    if (tid < 3) {
      float s = bbeta[tid];
      for (int j = 0; j < kKD; ++j) s = fmaf(s_qe[j], Wbeta[tid * kKD + j], s);
      v = tanhf(s);
    }
    ws[OFF_BQ + (size_t)q * 4 + tid] = v;
  }
  if (tid == 0) {
    float s = 0.f;
    for (int j = 0; j < kKD; ++j) s = fmaf(s_qe[j], Wdisc[kFC + j], s);
    ws[OFF_DQ + q] = s;
  }
}

// ---------------- shared finale ----------------
__device__ __forceinline__ void do_finale(int l, float wth_f, float wds_f, float bth0,
                                          float bdisc0, const float (*s_part)[64],
                                          const float* s_sq_row, const float* s_bqdq_row,
                                          float* out_ptr) {
  float summ = 0.f;
  if (l < kFC) {
    const float sp = s_part[0][l] + s_part[1][l] + s_part[2][l] + s_part[3][l] +
                     s_part[4][l] + s_sq_row[l];
    summ = fast_tanh(sp);
  }
  float p1 = wth_f * summ;
  float p2 = wds_f * summ;
#pragma unroll
  for (int o = 1; o < 64; o <<= 1) {
    p1 += __shfl_xor(p1, o);
    p2 += __shfl_xor(p2, o);
  }
  if (l == 0) {
    const float theta = 3.f * (p1 + bth0);
    const float alpha = fast_softplus(p2 + s_bqdq_row[3] + bdisc0);
    const float c1 = alpha * (theta - s_bqdq_row[0]);
    const float c2 = c1 + alpha * (theta - s_bqdq_row[1]);
    const float c3 = c2 + alpha * (theta - s_bqdq_row[2]);
    const float mx = fmaxf(fmaxf(0.f, c1), fmaxf(c2, c3));
    const float x0 = __expf(0.f - mx);
    const float x1 = __expf(c1 - mx);
    const float x2 = __expf(c2 - mx);
    const float x3 = __expf(c3 - mx);
    const float inv = 1.f / (x0 + x1 + x2 + x3);
    float4 pr;
    pr.x = x0 * inv;
    pr.y = x1 * inv;
    pr.z = x2 * inv;
    pr.w = x3 * inv;
    *reinterpret_cast<float4*>(out_ptr) = pr;
  }
}

// ================= SPLIT PATH: kernel 1, recurrence only =================
// One step: consume ea (t), cw (t) from ring; produce read[t] -> global f16.
// BR = (t)&3 ring slot to read, BW = (t+2)&3 slot to write (row t+2).
#define RSTEP(BR, BW, T, EAC, CWW)                                                    \
  {                                                                                   \
    f32x2 en2 = {0.f, 0.f}, ad2 = {0.f, 0.f};                                         \
    if (dact) {                                                                       \
      en2[0] = -EAC.x; en2[1] = -EAC.x;                                               \
      ad2[0] = EAC.y;  ad2[1] = EAC.y;                                                \
      EAC = EAD2[(size_t)s_qr[(T) + 2] * kD + d]; /* prefetch row T+2 */              \
    }                                                                                 \
    if (cwact) {                                                                      \
      s_cw[BW][cj] = CWW;                   /* stage cw row T+2 */                    \
      CWW = CW[s_q[(T) + 4] * kMem + cj];   /* prefetch row T+4 */                    \
    }                                                                                 \
    if (dact) {                                                                       \
      f32x2 r2a = {0.f, 0.f}, r2b = {0.f, 0.f};                                       \
      const float4* cw4_ = reinterpret_cast<const float4*>(s_cw[BR]);                 \
      _Pragma("unroll") for (int g = 0; g < 12; ++g) {                                \
        const float4 c4_ = cw4_[g];                                                   \
        const f32x2 clo_ = {c4_.x, c4_.y};                                            \
        const f32x2 chi_ = {c4_.z, c4_.w};                                            \
        r2a = pk_fma(clo_, mv[2 * g], r2a);                                           \
        mv[2 * g] = pk_fma(clo_, pk_fma(mv[2 * g], en2, ad2), mv[2 * g]);             \
        r2b = pk_fma(chi_, mv[2 * g + 1], r2b);                                       \
        mv[2 * g + 1] = pk_fma(chi_, pk_fma(mv[2 * g + 1], en2, ad2), mv[2 * g + 1]); \
      }                                                                               \
      {                                                                               \
        const f32x2 cl_ = *reinterpret_cast<const f32x2*>(&s_cw[BR][48]);             \
        r2a = pk_fma(cl_, mv[24], r2a);                                               \
        mv[24] = pk_fma(cl_, pk_fma(mv[24], en2, ad2), mv[24]);                       \
      }                                                                               \
      Rb[(size_t)(T) * kD + d] = (_Float16)((r2a[0] + r2b[0]) + (r2a[1] + r2b[1]));   \
    }                                                                                 \
  }

__launch_bounds__(256, 4)
__global__ void dkvmn_rec(const int* __restrict__ q_data, const int* __restrict__ r_data,
                          const float* __restrict__ Mv0, const float* __restrict__ ws,
                          _Float16* __restrict__ R) {
  const int tid = threadIdx.x;
  const int b = blockIdx.x;
  const float2* EAD2 = reinterpret_cast<const float2*>(ws + OFF_EAD);
  const float* CW = ws + OFF_CW;

  __shared__ __align__(16) float s_cw[4][64];  // 4-deep ring of attention rows
  __shared__ int s_q[504];                     // padded: [500..503] = [499]
  __shared__ int s_qr[504];

  {
    const int* qrow = q_data + (size_t)b * kS;
    const int* rrow = r_data + (size_t)b * kS;
    for (int e = tid; e < kS; e += 256) {
      const int qv = qrow[e];
      s_q[e] = qv;
      s_qr[e] = (qv - 1) * 4 + rrow[e];
    }
  }
  const int d = tid;
  const bool dact = (d < kD);
  const bool cwact = (tid >= 200 && tid < 250);
  const int cj = tid - 200;
  f32x2 mv[25];
#pragma unroll
  for (int m = 0; m < 25; ++m) mv[m] = f32x2{0.f, 0.f};
  if (dact) {
#pragma unroll
    for (int m = 0; m < 25; ++m) {
      mv[m][0] = Mv0[(2 * m) * kD + d];
      mv[m][1] = Mv0[(2 * m + 1) * kD + d];
    }
  }
  _Float16* Rb = R + (size_t)b * kS * kD;
  __syncthreads();  // s_q/s_qr filled
  if (tid < 4) {
    s_q[500 + tid] = s_q[499];
    s_qr[500 + tid] = s_qr[499];
  }
  // prologue: ring slots 0,1 = cw rows 0,1; regs hold rows 2 (even) / 3 (odd)
  float cwE = 0.f, cwO = 0.f;
  if (cwact) {
    s_cw[0][cj] = CW[s_q[0] * kMem + cj];
    s_cw[1][cj] = CW[s_q[1] * kMem + cj];
    cwE = CW[s_q[2] * kMem + cj];
    cwO = CW[s_q[3] * kMem + cj];
  }
  float2 eaE = make_float2(0.f, 0.f), eaO = eaE;
  if (dact) {
    eaE = EAD2[(size_t)s_qr[0] * kD + d];
    eaO = EAD2[(size_t)s_qr[1] * kD + d];
  }
  __syncthreads();  // pad + ring slots 0,1 visible

  // 125 groups of 4 steps; barrier every 2 steps; ring slots compile-time.
  for (int jt = 0; jt < 125; ++jt) {
    const int t0 = 4 * jt;
    RSTEP(0, 2, t0 + 0, eaE, cwE)
    RSTEP(1, 3, t0 + 1, eaO, cwO)
    lds_barrier();
    RSTEP(2, 0, t0 + 2, eaE, cwE)
    RSTEP(3, 1, t0 + 3, eaO, cwO)
    lds_barrier();
  }
}

// ================= SPLIT PATH: kernel 2, feed-forward head =================
__launch_bounds__(256, 4)
__global__ void dkvmn_head(const int* __restrict__ q_data, const _Float16* __restrict__ R,
                           const float* __restrict__ Ws, const float* __restrict__ Wth,
                           const float* __restrict__ bth, const float* __restrict__ Wdisc,
                           const float* __restrict__ bdisc, const float* __restrict__ ws,
                           float* __restrict__ out) {
  const int tid = threadIdx.x;
  const int b = blockIdx.x;
  const int lane = tid & 63;
  const int wid = tid >> 6;
  const float* SQ = ws + OFF_SQ;
  const float* BQ = ws + OFF_BQ;
  const float* DQ = ws + OFF_DQ;

  __shared__ __align__(16) _Float16 s_wsh[kFC * kWP];  // f16 Ws(:,0:200) [f][d], pitch 216
  __shared__ __align__(16) _Float16 s_readh[2][208];
  __shared__ float s_part[2][5][64];
  __shared__ float s_sq[3][52];
  __shared__ float s_bqdq[3][4];
  __shared__ int s_q[kS];

  for (int e = tid; e < kFC * kD; e += 256) {
    const int f = e / kD;
    const int dd = e - f * kD;
    s_wsh[f * kWP + dd] = (_Float16)Ws[f * 250 + dd];
  }
  {
    const int* qrow = q_data + (size_t)b * kS;
    for (int e = tid; e < kS; e += 256) s_q[e] = qrow[e];
  }
  const int pc = tid / 50;  // phase-2 mapping (tid<250)
  const int pf = tid - pc * 50;
  const bool ract = (tid >= 128 && tid < 228);  // R-row staging (100 dwords)
  const int ru = tid - 128;
  float wth_f = 0.f, wds_f = 0.f;
  if (wid == 0 && lane < kFC) {
    wth_f = Wth[lane];
    wds_f = Wdisc[lane];
  }
  const float bth0 = bth[0];
  const float bdisc0 = bdisc[0];
  const _Float16* Rb = R + (size_t)b * kS * kD;
  float* out_b = out + (size_t)b * kS * 4;
  __syncthreads();  // s_wsh + s_q visible

  // prologue: row 0 -> s_readh[0]; rv_cur <- row 1; SQ row 0 staged; v2_cur <- row 1
  unsigned int rv_cur = 0;
  if (ract) {
    *reinterpret_cast<unsigned int*>(&s_readh[0][2 * ru]) =
        reinterpret_cast<const unsigned int*>(Rb)[ru];
    rv_cur = reinterpret_cast<const unsigned int*>(Rb + kD)[ru];
  }
  float v2_cur = 0.f;
  if (wid == 1) {
    const int q0 = s_q[0];
    if (lane < kFC) s_sq[0][lane] = SQ[q0 * kFC + lane];
    else if (lane < 53) s_bqdq[0][lane - 50] = BQ[q0 * 4 + (lane - 50)];
    else if (lane == 53) s_bqdq[0][3] = DQ[q0];
    const int q1 = s_q[1];
    if (lane < kFC) v2_cur = SQ[q1 * kFC + lane];
    else if (lane < 53) v2_cur = BQ[q1 * 4 + (lane - 50)];
    else if (lane == 53) v2_cur = DQ[q1];
  }
  __syncthreads();  // row 0 + sq[0] visible

  for (int t = 0; t < kS; ++t) {
    const int pb = t & 1;
    // stage row t+1; prefetch row t+2
    if (ract) {
      *reinterpret_cast<unsigned int*>(&s_readh[pb ^ 1][2 * ru]) = rv_cur;
      const int t2 = (t + 2 < kS) ? t + 2 : kS - 1;
      rv_cur = reinterpret_cast<const unsigned int*>(Rb + (size_t)t2 * kD)[ru];
    }
    if (wid == 1) {  // sq for row t+1 (consumed by finale at iter t+2); prefetch t+2
      const int i3n = (t + 1) % 3;
      const int qn = s_q[(t + 2 < kS) ? t + 2 : kS - 1];
      if (lane < kFC) {
        s_sq[i3n][lane] = v2_cur;
        v2_cur = SQ[qn * kFC + lane];
      } else if (lane < 53) {
        s_bqdq[i3n][lane - 50] = v2_cur;
        v2_cur = BQ[qn * 4 + (lane - 50)];
      } else if (lane == 53) {
        s_bqdq[i3n][3] = v2_cur;
        v2_cur = DQ[qn];
      }
    }
    // phase 2: partials for row t (from s_readh[pb], staged at iter t-1)
    if (tid < 250) {
      const float4* wp = reinterpret_cast<const float4*>(s_wsh + pf * kWP + pc * 40);
      const float4* rp = reinterpret_cast<const float4*>(&s_readh[pb][pc * 40]);
      float acc0 = 0.f, acc1 = 0.f;
#pragma unroll
      for (int g = 0; g < 5; ++g) {
        const float4 wv = wp[g];
        const float4 rv = rp[g];
        acc0 = __builtin_amdgcn_fdot2(__builtin_bit_cast(h2_t, wv.x),
                                      __builtin_bit_cast(h2_t, rv.x), acc0, false);
        acc1 = __builtin_amdgcn_fdot2(__builtin_bit_cast(h2_t, wv.y),
                                      __builtin_bit_cast(h2_t, rv.y), acc1, false);
        acc0 = __builtin_amdgcn_fdot2(__builtin_bit_cast(h2_t, wv.z),
                                      __builtin_bit_cast(h2_t, rv.z), acc0, false);
        acc1 = __builtin_amdgcn_fdot2(__builtin_bit_cast(h2_t, wv.w),
                                      __builtin_bit_cast(h2_t, rv.w), acc1, false);
      }
      s_part[pb][pc][pf] = acc0 + acc1;
    }
    // finale for row t-1 (partials written at iter t-1)
    if (wid == 0 && t >= 1) {
      const int i3p = (t - 1) % 3;
      do_finale(lane, wth_f, wds_f, bth0, bdisc0, s_part[pb ^ 1], s_sq[i3p], s_bqdq[i3p],
                out_b + (size_t)(t - 1) * 4);
    }
    lds_barrier();
  }
  // epilogue: finale for row kS-1
  if (wid == 0) {
    do_finale(lane, wth_f, wds_f, bth0, bdisc0, s_part[(kS - 1) & 1], s_sq[(kS - 1) % 3],
              s_bqdq[(kS - 1) % 3], out_b + (size_t)(kS - 1) * 4);
  }
}

// ================= FALLBACK: proven R9 fused kernel (unchanged) =================
#define STEP(PB, I3, T, TN1, TN2)                                                     \
  {                                                                                   \
    constexpr int IP1_ = ((I3) + 1) % 3;                                              \
    f32x2 en2 = {0.f, 0.f}, ad2 = {0.f, 0.f};                                         \
    float2 ea_nxt = ea_cur;                                                           \
    if (dact) {                                                                       \
      ea_nxt = EAD2[(size_t)s_qr[(TN1)] * kD + d];                                    \
      en2[0] = -ea_cur.x;                                                             \
      en2[1] = -ea_cur.x;                                                             \
      ad2[0] = ea_cur.y;                                                              \
      ad2[1] = ea_cur.y;                                                              \
    }                                                                                 \
    if (wid == 0 && lane < kMem) {                                                    \
      s_cw[(PB) ^ 1][lane] = cw_cur;                                                  \
      cw_cur = CW[s_q[(TN2)] * kMem + lane];                                          \
    }                                                                                 \
    if (wid == 1) {                                                                   \
      const int qn_ = s_q[(TN1)];                                                     \
      if (lane < kFC) {                                                               \
        s_sq[(I3)][lane] = v2_cur;                                                    \
        v2_cur = SQ[qn_ * kFC + lane];                                                \
      } else if (lane < 53) {                                                         \
        s_bqdq[(I3)][lane - 50] = v2_cur;                                             \
        v2_cur = BQ[qn_ * 4 + (lane - 50)];                                           \
      } else if (lane == 53) {                                                        \
        s_bqdq[(I3)][3] = v2_cur;                                                     \
        v2_cur = DQ[qn_];                                                             \
      }                                                                               \
    }                                                                                 \
    if (dact) {                                                                       \
      f32x2 r2a = {0.f, 0.f}, r2b = {0.f, 0.f};                                       \
      const float4* cw4_ = reinterpret_cast<const float4*>(s_cw[(PB)]);               \
      _Pragma("unroll") for (int g = 0; g < 12; ++g) {                                \
        const float4 c4_ = cw4_[g];                                                   \
        const f32x2 clo_ = {c4_.x, c4_.y};                                            \
        const f32x2 chi_ = {c4_.z, c4_.w};                                            \
        r2a = pk_fma(clo_, mv[2 * g], r2a);                                           \
        mv[2 * g] = pk_fma(clo_, pk_fma(mv[2 * g], en2, ad2), mv[2 * g]);             \
        r2b = pk_fma(chi_, mv[2 * g + 1], r2b);                                       \
        mv[2 * g + 1] = pk_fma(chi_, pk_fma(mv[2 * g + 1], en2, ad2), mv[2 * g + 1]); \
      }                                                                               \
      {                                                                               \
        const f32x2 cl_ = *reinterpret_cast<const f32x2*>(&s_cw[(PB)][48]);           \
        r2a = pk_fma(cl_, mv[24], r2a);                                               \
        mv[24] = pk_fma(cl_, pk_fma(mv[24], en2, ad2), mv[24]);                       \
      }                                                                               \
      s_readh[(PB)][d] = (_Float16)((r2a[0] + r2b[0]) + (r2a[1] + r2b[1]));           \
    }                                                                                 \
    if (wid == 0 && (T) >= 2) {                                                       \
      do_finale(lane, wth_f, wds_f, bth0, bdisc0, s_part[(PB) ^ 1], s_sq[IP1_],       \
                s_bqdq[IP1_], out_b + (size_t)((T) - 2) * 4);                         \
    }                                                                                 \
    if (tid < 250) {                                                                  \
      const float4* wp_ = reinterpret_cast<const float4*>(s_wsh + pf * kWP + pc * 40);\
      const float4* rp_ = reinterpret_cast<const float4*>(&s_readh[(PB) ^ 1][pc * 40]);\
      float a0_ = 0.f, a1_ = 0.f;                                                     \
      _Pragma("unroll") for (int g = 0; g < 5; ++g) {                                 \
        const float4 wv_ = wp_[g];                                                    \
        const float4 rv_ = rp_[g];                                                    \
        a0_ = __builtin_amdgcn_fdot2(__builtin_bit_cast(h2_t, wv_.x),                 \
                                     __builtin_bit_cast(h2_t, rv_.x), a0_, false);    \
        a1_ = __builtin_amdgcn_fdot2(__builtin_bit_cast(h2_t, wv_.y),                 \
                                     __builtin_bit_cast(h2_t, rv_.y), a1_, false);    \
        a0_ = __builtin_amdgcn_fdot2(__builtin_bit_cast(h2_t, wv_.z),                 \
                                     __builtin_bit_cast(h2_t, rv_.z), a0_, false);    \
        a1_ = __builtin_amdgcn_fdot2(__builtin_bit_cast(h2_t, wv_.w),                 \
                                     __builtin_bit_cast(h2_t, rv_.w), a1_, false);    \
      }                                                                               \
      s_part[(PB)][pc][pf] = a0_ + a1_;                                               \
    }                                                                                 \
    lds_barrier();                                                                    \
    ea_cur = ea_nxt;                                                                  \
  }

__launch_bounds__(256, 4)
__global__ void dkvmn_main(const int* __restrict__ q_data, const int* __restrict__ r_data,
                           const float* __restrict__ Mv0, const float* __restrict__ Ws,
                           const float* __restrict__ Wth, const float* __restrict__ bth,
                           const float* __restrict__ Wdisc, const float* __restrict__ bdisc,
                           const float* __restrict__ ws, float* __restrict__ out) {
  const int tid = threadIdx.x;
  const int b = blockIdx.x;
  const int lane = tid & 63;
  const int wid = tid >> 6;
  const float2* EAD2 = reinterpret_cast<const float2*>(ws + OFF_EAD);
  const float* CW = ws + OFF_CW;
  const float* SQ = ws + OFF_SQ;
  const float* BQ = ws + OFF_BQ;
  const float* DQ = ws + OFF_DQ;

  __shared__ __align__(16) _Float16 s_wsh[kFC * kWP];
  __shared__ __align__(16) _Float16 s_readh[2][208];
  __shared__ __align__(16) float s_cw[2][64];
  __shared__ float s_part[2][5][64];
  __shared__ float s_sq[3][52];
  __shared__ float s_bqdq[3][4];
  __shared__ int s_q[kS];
  __shared__ int s_qr[kS];

  for (int e = tid; e < kFC * kD; e += 256) {
    const int f = e / kD;
    const int dd = e - f * kD;
    s_wsh[f * kWP + dd] = (_Float16)Ws[f * 250 + dd];
  }
  {
    const int* qrow = q_data + (size_t)b * kS;
    const int* rrow = r_data + (size_t)b * kS;
    for (int e = tid; e < kS; e += 256) {
      const int qv = qrow[e];
      s_q[e] = qv;
      s_qr[e] = (qv - 1) * 4 + rrow[e];
    }
  }
  const int d = tid;
  const bool dact = (d < kD);
  const int pc = tid / 50;
  const int pf = tid - pc * 50;
  f32x2 mv[25];
#pragma unroll
  for (int m = 0; m < 25; ++m) mv[m] = f32x2{0.f, 0.f};
  if (dact) {
#pragma unroll
    for (int m = 0; m < 25; ++m) {
      mv[m][0] = Mv0[(2 * m) * kD + d];
      mv[m][1] = Mv0[(2 * m + 1) * kD + d];
    }
  }
  float wth_f = 0.f, wds_f = 0.f;
  if (wid == 0 && lane < kFC) {
    wth_f = Wth[lane];
    wds_f = Wdisc[lane];
  }
  const float bth0 = bth[0];
  const float bdisc0 = bdisc[0];
  float* out_b = out + (size_t)b * kS * 4;
  __syncthreads();

  const int q0 = s_q[0];
  const int q1 = s_q[1];
  float2 ea_cur = make_float2(0.f, 0.f);
  if (dact) ea_cur = EAD2[(size_t)s_qr[0] * kD + d];
  float cw_cur = 0.f;
  if (wid == 0 && lane < kMem) {
    s_cw[0][lane] = CW[q0 * kMem + lane];
    cw_cur = CW[q1 * kMem + lane];
  }
  float v2_cur = 0.f;
  if (wid == 1) {
    if (lane < kFC) v2_cur = SQ[q0 * kFC + lane];
    else if (lane < 53) v2_cur = BQ[q0 * 4 + (lane - 50)];
    else if (lane == 53) v2_cur = DQ[q0];
  }
  __syncthreads();

  for (int it = 0; it < 83; ++it) {
    const int t0 = 6 * it;
    STEP(0, 0, t0 + 0, t0 + 1, t0 + 2)
    STEP(1, 1, t0 + 1, t0 + 2, t0 + 3)
    STEP(0, 2, t0 + 2, t0 + 3, t0 + 4)
    STEP(1, 0, t0 + 3, t0 + 4, t0 + 5)
    STEP(0, 1, t0 + 4, t0 + 5, t0 + 6)
    STEP(1, 2, t0 + 5, t0 + 6, t0 + 7)
  }
  STEP(0, 0, 498, 499, 499)
  STEP(1, 1, 499, 499, 499)

  {
    constexpr int pbE = kS & 1;
    constexpr int i3a = (kS - 2) % 3;
    constexpr int i3b = (kS - 1) % 3;
    if (tid < 250) {
      const float4* wp = reinterpret_cast<const float4*>(s_wsh + pf * kWP + pc * 40);
      const float4* rp = reinterpret_cast<const float4*>(&s_readh[(kS - 1) & 1][pc * 40]);
      float acc0 = 0.f, acc1 = 0.f;
#pragma unroll
      for (int g = 0; g < 5; ++g) {
        const float4 wv = wp[g];
        const float4 rv = rp[g];
        acc0 = __builtin_amdgcn_fdot2(__builtin_bit_cast(h2_t, wv.x),
                                      __builtin_bit_cast(h2_t, rv.x), acc0, false);
        acc1 = __builtin_amdgcn_fdot2(__builtin_bit_cast(h2_t, wv.y),
                                      __builtin_bit_cast(h2_t, rv.y), acc1, false);
        acc0 = __builtin_amdgcn_fdot2(__builtin_bit_cast(h2_t, wv.z),
                                      __builtin_bit_cast(h2_t, rv.z), acc0, false);
        acc1 = __builtin_amdgcn_fdot2(__builtin_bit_cast(h2_t, wv.w),
                                      __builtin_bit_cast(h2_t, rv.w), acc1, false);
      }
      s_part[pbE][pc][pf] = acc0 + acc1;
    }
    if (wid == 0) {
      do_finale(lane, wth_f, wds_f, bth0, bdisc0, s_part[pbE ^ 1], s_sq[i3a], s_bqdq[i3a],
                out_b + (size_t)(kS - 2) * 4);
    }
    lds_barrier();
    if (wid == 0) {
      do_finale(lane, wth_f, wds_f, bth0, bdisc0, s_part[pbE], s_sq[i3b], s_bqdq[i3b],
                out_b + (size_t)(kS - 1) * 4);
    }
  }
}

extern "C" void kernel_launch(void* const* d_in, const int* in_sizes, int n_in,
                              void* d_out, int out_size, void* d_ws, size_t ws_size,
                              hipStream_t stream) {
  (void)in_sizes; (void)n_in; (void)out_size;
  const int* q_data = (const int*)d_in[0];
  const int* r_data = (const int*)d_in[1];
  const float* q_embed_w = (const float*)d_in[2];
  const float* Mk = (const float*)d_in[3];
  const float* Mv0 = (const float*)d_in[4];
  const float* Wv = (const float*)d_in[5];
  const float* bv = (const float*)d_in[6];
  const float* We = (const float*)d_in[7];
  const float* be = (const float*)d_in[8];
  const float* Wa = (const float*)d_in[9];
  const float* ba = (const float*)d_in[10];
  const float* Ws = (const float*)d_in[11];
  const float* bs = (const float*)d_in[12];
  const float* Wth = (const float*)d_in[13];
  const float* bth = (const float*)d_in[14];
  const float* Wbeta = (const float*)d_in[15];
  const float* bbeta = (const float*)d_in[16];
  const float* Wdisc = (const float*)d_in[17];
  const float* bdisc = (const float*)d_in[18];
  float* out = (float*)d_out;
  float* ws = (float*)d_ws;

  hipLaunchKernelGGL(prep1_misc, dim3(64), dim3(256), 0, stream, We, Wa, bv, be, ba, ws);
  hipLaunchKernelGGL(prep2_ead, dim3(kQ), dim3(256), 0, stream, Wv, ws);
  hipLaunchKernelGGL(prep3_qtables, dim3(kQ + 1), dim3(64), 0, stream, q_embed_w, Mk, Ws, bs,
                     Wbeta, bbeta, Wdisc, ws);
  if (ws_size >= NEED_WS) {
    _Float16* R = reinterpret_cast<_Float16*>(ws + OFF_R);
    hipLaunchKernelGGL(dkvmn_rec, dim3(kB), dim3(256), 0, stream, q_data, r_data, Mv0, ws, R);
    hipLaunchKernelGGL(dkvmn_head, dim3(kB), dim3(256), 0, stream, q_data, R, Ws, Wth, bth,
                       Wdisc, bdisc, ws, out);
  } else {
    hipLaunchKernelGGL(dkvmn_main, dim3(kB), dim3(256), 0, stream, q_data, r_data, Mv0, Ws, Wth,
                       bth, Wdisc, bdisc, ws, out);
  }
}